// Round 7
// baseline (1557.066 us; speedup 1.0000x reference)
//
#include <hip/hip_runtime.h>
#include <hip/hip_bf16.h>

typedef __bf16 bf16_t;
typedef __bf16 bf16x8_t __attribute__((ext_vector_type(8)));
typedef __bf16 bf16x4_t __attribute__((ext_vector_type(4)));
typedef float f32x4_t __attribute__((ext_vector_type(4)));

#define EPI_RES_BF16 1
#define EPI_RELU_RES 2
#define EPI_BIAS 3

// async 16B global -> LDS (gfx950 global_load_lds_dwordx4)
__device__ __forceinline__ void gload_lds16(const bf16_t* g, bf16_t* l) {
  __builtin_amdgcn_global_load_lds(
      (const __attribute__((address_space(1))) void*)g,
      (__attribute__((address_space(3))) void*)l, 16, 0, 0);
}

__device__ __forceinline__ bf16x8_t ds_read_b128_bf16(unsigned addr) {
  bf16x8_t r;
  asm volatile("ds_read_b128 %0, %1" : "=v"(r) : "v"(addr));
  return r;
}

#define WAIT_VM(n) asm volatile("s_waitcnt vmcnt(" #n ")" ::: "memory")
#define WAIT_LGKM(n) asm volatile("s_waitcnt lgkmcnt(" #n ")" ::: "memory")
#define SCHED_FENCE __builtin_amdgcn_sched_barrier(0)

// ===========================================================================
// 256x256 merged-phase bf16 GEMM (scores): C = alpha * A @ Bt^T.
// 512 thr = 8 waves (2M x 4N), per-wave 128x64, BK=64 as 2 chunk-phases of 32.
// Chunk ring: 4 slots/operand (16 KiB each), staged 3 chunks ahead,
// counted vmcnt(8); per phase 12 ds_read + 32 MFMA with counted-lgkm split.
// __launch_bounds__(512,2): 2 waves/EU min -> 256-VGPR budget (NO SPILL;
// the default 512-thread heuristic caps at 128 and spilled acc to scratch).
// ===========================================================================
__global__ __launch_bounds__(512, 2) void gemm256_bt_scale(
    const bf16_t* __restrict__ A, long aBatch, int lda,
    const bf16_t* __restrict__ Bt, long bBatch, int ldb,
    float* __restrict__ C, long cBatch, int ldc,
    float alpha, int K)
{
  extern __shared__ char smem[];
  typedef __attribute__((address_space(3))) char lds_char_t;
  const unsigned ldsBase = (unsigned)(size_t)(lds_char_t*)smem;

  const unsigned gx = gridDim.x, gy = gridDim.y;
  const unsigned nwg = gx * gy * gridDim.z;
  const unsigned lin = blockIdx.x + gx * (blockIdx.y + gy * blockIdx.z);
  const unsigned swz = (lin & 7u) * (nwg >> 3) + (lin >> 3);
  const unsigned bx = swz % gx;
  const unsigned tq = swz / gx;
  const unsigned by = tq % gy;
  const unsigned bz = tq / gy;

  A += (long)bz * aBatch;
  Bt += (long)bz * bBatch;
  C += (long)bz * cBatch;

  const int tid = threadIdx.x, wid = tid >> 6, lane = tid & 63;
  const int wm = wid >> 2, wn = wid & 3;     // 2M x 4N waves; per-wave 128x64
  const int lr = lane & 15, lh = lane >> 4;
  const int sw2 = ((lr >> 3) & 1) << 1;
  const unsigned cbyte = (unsigned)((lh ^ sw2) << 4);

  const int gsw = ((lane >> 5) & 1) << 1;
  const int gcol = ((lane & 3) ^ gsw) << 3;
  const int grow = wid * 16 + (lane >> 2);
  const bf16_t* Ag = A + (long)(by * 256 + grow) * lda + gcol;
  const bf16_t* Bg = Bt + (long)(bx * 256 + grow) * ldb + gcol;

  // chunk n covers k = n*32..n*32+31; slot = n & 3 (A at slot*16K, B at +64K)
#define STAGE_CH(N_, SLOT) do { \
    const bf16_t* _sa = Ag + (long)(N_) * 32; \
    bf16_t* _da = (bf16_t*)(smem + (SLOT) * 16384 + wid * 1024); \
    gload_lds16(_sa, _da); \
    gload_lds16(_sa + (long)128 * lda, (bf16_t*)((char*)_da + 8192)); \
    const bf16_t* _sb = Bg + (long)(N_) * 32; \
    bf16_t* _db = (bf16_t*)(smem + 65536 + (SLOT) * 16384 + wid * 1024); \
    gload_lds16(_sb, _db); \
    gload_lds16(_sb + (long)128 * ldb, (bf16_t*)((char*)_db + 8192)); \
  } while (0)

  const unsigned aAddr = ldsBase + (unsigned)((wm * 128 + lr) * 64) + cbyte;
  const unsigned bAddr = ldsBase + 65536u + (unsigned)((wn * 64 + lr) * 64) + cbyte;

  bf16x8_t aF[4], aG[4], bF[4];
  f32x4_t acc[8][4] = {};

#define MF16(AB, AF) do { \
    __builtin_amdgcn_s_setprio(1); \
    _Pragma("unroll") for (int _n = 0; _n < 4; ++_n) \
      _Pragma("unroll") for (int _m = 0; _m < 4; ++_m) \
        acc[(AB) + _m][_n] = __builtin_amdgcn_mfma_f32_16x16x32_bf16( \
            AF[_m], bF[_n], acc[(AB) + _m][_n], 0, 0, 0); \
    __builtin_amdgcn_s_setprio(0); \
  } while (0)

#define SPHASE(SLOT, STAGE_STMT, VM_STMT) do { \
    const unsigned _sb = (unsigned)(SLOT) * 16384u; \
    _Pragma("unroll") for (int _m = 0; _m < 4; ++_m) \
      aF[_m] = ds_read_b128_bf16(aAddr + _sb + _m * 1024u); \
    _Pragma("unroll") for (int _n = 0; _n < 4; ++_n) \
      bF[_n] = ds_read_b128_bf16(bAddr + _sb + _n * 1024u); \
    _Pragma("unroll") for (int _m = 0; _m < 4; ++_m) \
      aG[_m] = ds_read_b128_bf16(aAddr + _sb + 4096u + _m * 1024u); \
    STAGE_STMT; \
    VM_STMT; \
    __builtin_amdgcn_s_barrier(); \
    WAIT_LGKM(4); \
    SCHED_FENCE; \
    MF16(0, aF); \
    WAIT_LGKM(0); \
    SCHED_FENCE; \
    MF16(4, aG); \
    __builtin_amdgcn_s_barrier(); \
    SCHED_FENCE; \
  } while (0)

  const int nt = K >> 6;  // >= 2

  // prologue: chunks 0,1,2 into slots 0,1,2; retire chunk 0 (vm in-order)
  STAGE_CH(0, 0); STAGE_CH(1, 1); STAGE_CH(2, 2);
  WAIT_VM(8);
  __builtin_amdgcn_s_barrier();
  SCHED_FENCE;

  int bufc = 0;
  for (int kt = 0; kt < nt; ++kt, bufc ^= 1) {
    const int s0 = bufc * 2, s1 = s0 + 1;
    const int sA = ((bufc ^ 1) << 1) + 1;  // slot for chunk 2kt+3
    // phase n=2kt (H0): stage chunk 2kt+3; retire chunk 2kt+1
    if (kt + 1 < nt) {
      SPHASE(s0, STAGE_CH(2 * kt + 3, sA), WAIT_VM(8));
    } else {
      SPHASE(s0, (void)0, WAIT_VM(0));
    }
    // phase n=2kt+1 (H1): stage chunk 2kt+4 into s0; retire chunk 2kt+2
    if (kt + 2 < nt) {
      SPHASE(s1, STAGE_CH(2 * kt + 4, s0), WAIT_VM(8));
    } else if (kt + 1 < nt) {
      SPHASE(s1, (void)0, WAIT_VM(4));
    } else {
      SPHASE(s1, (void)0, WAIT_VM(0));
    }
  }

  const long r0 = (long)by * 256 + wm * 128;
  const int c0 = bx * 256 + wn * 64;
#pragma unroll
  for (int m = 0; m < 8; ++m)
#pragma unroll
    for (int n = 0; n < 4; ++n)
#pragma unroll
      for (int r = 0; r < 4; ++r)
        C[(r0 + m * 16 + lh * 4 + r) * ldc + c0 + n * 16 + lr] = acc[m][n][r] * alpha;

#undef SPHASE
#undef MF16
#undef STAGE_CH
}

// ===========================================================================
// 256x128 merged-phase bf16 GEMM (PV/FFN/proj): one barrier-pair per K-tile.
// 512 thr = 8 waves (4M x 2N), per-wave 64x64, BK=64. Ring-3 K-tile buffers
// (A 3x32 KiB + B 3x16 KiB = 144 KiB LDS). Per K-tile: 16 ds_read + 32 MFMA,
// counted-lgkm split, counted vmcnt(6). __launch_bounds__(512,2): 256-VGPR
// budget so acc+4 frag sets never spill.
// ===========================================================================
template <int EPI>
__global__ __launch_bounds__(512, 2) void gemm_pv(
    const bf16_t* __restrict__ A, long aBatch, int lda,
    const bf16_t* __restrict__ Bt, long bBatch, int ldb,
    float* __restrict__ Cf, long cfBatch, int ldc,
    bf16_t* __restrict__ Cb, long cbBatch,
    const float* __restrict__ Res, long resBatch,
    const float* __restrict__ bias, int K)
{
  extern __shared__ char smem[];
  typedef __attribute__((address_space(3))) char lds_char_t;
  const unsigned ldsBase = (unsigned)(size_t)(lds_char_t*)smem;

  const unsigned gx = gridDim.x, gy = gridDim.y;
  const unsigned nwg = gx * gy * gridDim.z;
  const unsigned lin = blockIdx.x + gx * (blockIdx.y + gy * blockIdx.z);
  const unsigned swz = (lin & 7u) * (nwg >> 3) + (lin >> 3);
  const unsigned bx = swz % gx;
  const unsigned tq = swz / gx;
  const unsigned by = tq % gy;
  const unsigned bz = tq / gy;

  A += (long)bz * aBatch;
  Bt += (long)bz * bBatch;
  Cf += (long)bz * cfBatch;
  if (Cb) Cb += (long)bz * cbBatch;
  if (Res) Res += (long)bz * resBatch;

  const int tid = threadIdx.x, wid = tid >> 6, lane = tid & 63;
  const int wm = wid >> 1, wn = wid & 1;     // 4M x 2N waves; per-wave 64x64
  const int lr = lane & 15, lh = lane >> 4;
  const int sw2 = ((lr >> 3) & 1) << 1;
  const unsigned cbyte = (unsigned)((lh ^ sw2) << 4);

  const int gsw = ((lane >> 5) & 1) << 1;
  const int gcol = ((lane & 3) ^ gsw) << 3;
  const int grow = wid * 16 + (lane >> 2);
  const bf16_t* Ag = A + (long)(by * 256 + grow) * lda + gcol;
  const bf16_t* Bg = Bt + (long)(bx * 128 + grow) * ldb + gcol;

  // LDS: A at so*32768 + H*16384 (3 K-tile slots); B at 98304 + so*16384 + H*8192
#define STAGE_KT(KT, SO) do { \
    const bf16_t* _sa = Ag + (long)(KT) * 64; \
    char* _da = smem + (SO) * 32768 + wid * 1024; \
    gload_lds16(_sa, (bf16_t*)_da); \
    gload_lds16(_sa + (long)128 * lda, (bf16_t*)(_da + 8192)); \
    gload_lds16(_sa + 32, (bf16_t*)(_da + 16384)); \
    gload_lds16(_sa + (long)128 * lda + 32, (bf16_t*)(_da + 16384 + 8192)); \
    const bf16_t* _sb = Bg + (long)(KT) * 64; \
    char* _db = smem + 98304 + (SO) * 16384 + wid * 1024; \
    gload_lds16(_sb, (bf16_t*)_db); \
    gload_lds16(_sb + 32, (bf16_t*)(_db + 8192)); \
  } while (0)

  const unsigned aAddr = ldsBase + (unsigned)((wm * 64 + lr) * 64) + cbyte;
  const unsigned bAddr = ldsBase + 98304u + (unsigned)((wn * 64 + lr) * 64) + cbyte;

  bf16x8_t aF[4], aG[4], bF[4], bG[4];
  f32x4_t acc[4][4] = {};

#define PPHASE(SO, STAGE_STMT, VM_STMT) do { \
    const unsigned _ab = aAddr + (unsigned)(SO) * 32768u; \
    const unsigned _bb = bAddr + (unsigned)(SO) * 16384u; \
    _Pragma("unroll") for (int _m = 0; _m < 4; ++_m) \
      aF[_m] = ds_read_b128_bf16(_ab + _m * 1024u); \
    _Pragma("unroll") for (int _n = 0; _n < 4; ++_n) \
      bF[_n] = ds_read_b128_bf16(_bb + _n * 1024u); \
    _Pragma("unroll") for (int _m = 0; _m < 4; ++_m) \
      aG[_m] = ds_read_b128_bf16(_ab + 16384u + _m * 1024u); \
    _Pragma("unroll") for (int _n = 0; _n < 4; ++_n) \
      bG[_n] = ds_read_b128_bf16(_bb + 8192u + _n * 1024u); \
    STAGE_STMT; \
    VM_STMT; \
    __builtin_amdgcn_s_barrier(); \
    WAIT_LGKM(8); \
    SCHED_FENCE; \
    __builtin_amdgcn_s_setprio(1); \
    _Pragma("unroll") for (int _n = 0; _n < 4; ++_n) \
      _Pragma("unroll") for (int _m = 0; _m < 4; ++_m) \
        acc[_m][_n] = __builtin_amdgcn_mfma_f32_16x16x32_bf16(aF[_m], bF[_n], acc[_m][_n], 0, 0, 0); \
    __builtin_amdgcn_s_setprio(0); \
    WAIT_LGKM(0); \
    SCHED_FENCE; \
    __builtin_amdgcn_s_setprio(1); \
    _Pragma("unroll") for (int _n = 0; _n < 4; ++_n) \
      _Pragma("unroll") for (int _m = 0; _m < 4; ++_m) \
        acc[_m][_n] = __builtin_amdgcn_mfma_f32_16x16x32_bf16(aG[_m], bG[_n], acc[_m][_n], 0, 0, 0); \
    __builtin_amdgcn_s_setprio(0); \
    __builtin_amdgcn_s_barrier(); \
    SCHED_FENCE; \
  } while (0)

  const int nt = K >> 6;  // >= 3

  STAGE_KT(0, 0); STAGE_KT(1, 1);   // 12 loads; retire K-tile 0
  WAIT_VM(6);
  __builtin_amdgcn_s_barrier();
  SCHED_FENCE;

  int so = 0;
  for (int kt = 0; kt < nt; ++kt) {
    int sn = so + 2; if (sn >= 3) sn -= 3;
    if (kt + 2 < nt) {
      PPHASE(so, STAGE_KT(kt + 2, sn), WAIT_VM(6));
    } else {
      PPHASE(so, (void)0, WAIT_VM(0));
    }
    so += 1; if (so >= 3) so = 0;
  }

  // epilogue: C/D layout col = lane&15, row = (lane>>4)*4 + reg
  const long r0 = (long)by * 256 + wm * 64;
  const int c0 = bx * 128 + wn * 64;
#pragma unroll
  for (int m = 0; m < 4; ++m) {
#pragma unroll
    for (int n = 0; n < 4; ++n) {
#pragma unroll
      for (int r = 0; r < 4; ++r) {
        const long row = r0 + m * 16 + lh * 4 + r;
        const int col = c0 + n * 16 + lr;
        const float v = acc[m][n][r];
        if constexpr (EPI == EPI_BIAS) {
          Cf[row * ldc + col] = v + bias[col];
        } else if constexpr (EPI == EPI_RES_BF16) {
          const float o = Res[row * ldc + col] + v;
          Cf[row * ldc + col] = o;
          Cb[row * ldc + col] = (bf16_t)o;
        } else {  // EPI_RELU_RES
          float t = v + bias[col];
          t = t > 0.f ? t : 0.f;
          const float o = Res[row * ldc + col] + t;
          Cf[row * ldc + col] = o;
          Cb[row * ldc + col] = (bf16_t)o;
        }
      }
    }
  }
#undef PPHASE
#undef STAGE_KT
}

// ---------------------------------------------------------------------------
// Row softmax over S f32 values, in-place bf16 writeback (rows at f32 stride,
// so P is later read with lda = 2*S bf16 elems). One block (256 thr) per row.
// ---------------------------------------------------------------------------
__global__ __launch_bounds__(256) void softmax_rows(float* __restrict__ scores, int S)
{
  const long row = blockIdx.x;
  float* p = scores + row * (long)S;
  const int t = threadIdx.x;
  const int lane = t & 63, wave = t >> 6;

  float4 v0 = ((const float4*)p)[t * 2];
  float4 v1 = ((const float4*)p)[t * 2 + 1];
  float e[8] = {v0.x, v0.y, v0.z, v0.w, v1.x, v1.y, v1.z, v1.w};

  float m = e[0];
#pragma unroll
  for (int j = 1; j < 8; ++j) m = fmaxf(m, e[j]);
#pragma unroll
  for (int off = 32; off >= 1; off >>= 1) m = fmaxf(m, __shfl_xor(m, off));

  __shared__ float redm[4], reds[4];
  if (lane == 0) redm[wave] = m;
  __syncthreads();
  m = fmaxf(fmaxf(redm[0], redm[1]), fmaxf(redm[2], redm[3]));

  float s = 0.f;
#pragma unroll
  for (int j = 0; j < 8; ++j) { e[j] = __expf(e[j] - m); s += e[j]; }
#pragma unroll
  for (int off = 32; off >= 1; off >>= 1) s += __shfl_xor(s, off);
  if (lane == 0) reds[wave] = s;
  __syncthreads();
  s = reds[0] + reds[1] + reds[2] + reds[3];
  const float inv = 1.f / s;

  bf16x8_t ob;
#pragma unroll
  for (int j = 0; j < 8; ++j) ob[j] = (bf16_t)(e[j] * inv);
  ((bf16x8_t*)p)[t] = ob;
}

// ---------------------------------------------------------------------------
__global__ void cast_copy(const float* __restrict__ in, float* __restrict__ outf,
                          bf16_t* __restrict__ outb, long n4)
{
  long i = (long)blockIdx.x * blockDim.x + threadIdx.x;
  const long stride = (long)gridDim.x * blockDim.x;
  for (; i < n4; i += stride) {
    float4 v = ((const float4*)in)[i];
    ((float4*)outf)[i] = v;
    bf16x4_t bv;
    bv[0] = (bf16_t)v.x; bv[1] = (bf16_t)v.y; bv[2] = (bf16_t)v.z; bv[3] = (bf16_t)v.w;
    ((bf16x4_t*)outb)[i] = bv;
  }
}

// ---------------------------------------------------------------------------
__global__ void transpose_cast(const float* __restrict__ in, long inBatch, int R, int C,
                               bf16_t* __restrict__ out, long outBatch)
{
  __shared__ float tile[32][33];
  const float* src = in + (long)blockIdx.z * inBatch;
  bf16_t* dst = out + (long)blockIdx.z * outBatch;
  const int c0 = blockIdx.x * 32, r0 = blockIdx.y * 32;
  const int tx = threadIdx.x, ty = threadIdx.y;
#pragma unroll
  for (int i = 0; i < 32; i += 8) tile[ty + i][tx] = src[(long)(r0 + ty + i) * C + (c0 + tx)];
  __syncthreads();
#pragma unroll
  for (int i = 0; i < 32; i += 8)
    dst[(long)(c0 + ty + i) * R + (r0 + tx)] = (bf16_t)tile[tx][ty + i];
}

// ---------------------------------------------------------------------------
extern "C" void kernel_launch(void* const* d_in, const int* in_sizes, int n_in,
                              void* d_out, int out_size, void* d_ws, size_t ws_size,
                              hipStream_t stream)
{
  constexpr int L = 4, NB = 4, S = 2048, D = 1024;
  const float* x  = (const float*)d_in[0];
  const float* W  = (const float*)d_in[1];
  const float* bv = (const float*)d_in[2];
  const float* Wo = (const float*)d_in[3];
  const float* bo = (const float*)d_in[4];

  char* ws = (char*)d_ws;
  size_t off = 0;
  float* scores = (float*)(ws + off); off += (size_t)NB * S * S * 4;
  float* xf = (float*)(ws + off); off += (size_t)NB * S * D * 4;
  float* yf = (float*)(ws + off); off += (size_t)NB * S * D * 4;
  bf16_t* xb  = (bf16_t*)(ws + off); off += (size_t)NB * S * D * 2;
  bf16_t* xbT = (bf16_t*)(ws + off); off += (size_t)NB * S * D * 2;
  bf16_t* yb  = (bf16_t*)(ws + off); off += (size_t)NB * S * D * 2;
  bf16_t* WbT  = (bf16_t*)(ws + off); off += (size_t)L * D * D * 2;
  bf16_t* WobT = (bf16_t*)(ws + off); off += (size_t)D * D * 2;

  hipFuncSetAttribute((const void*)gemm256_bt_scale,
                      hipFuncAttributeMaxDynamicSharedMemorySize, 131072);
  hipFuncSetAttribute((const void*)gemm_pv<EPI_RES_BF16>,
                      hipFuncAttributeMaxDynamicSharedMemorySize, 147456);
  hipFuncSetAttribute((const void*)gemm_pv<EPI_RELU_RES>,
                      hipFuncAttributeMaxDynamicSharedMemorySize, 147456);
  hipFuncSetAttribute((const void*)gemm_pv<EPI_BIAS>,
                      hipFuncAttributeMaxDynamicSharedMemorySize, 147456);

  const long n4 = (long)NB * S * D / 4;
  cast_copy<<<2048, 256, 0, stream>>>(x, xf, xb, n4);
  transpose_cast<<<dim3(D / 32, S / 32, NB), dim3(32, 8), 0, stream>>>(
      x, (long)S * D, S, D, xbT, (long)D * S);
  transpose_cast<<<dim3(D / 32, D / 32, L), dim3(32, 8), 0, stream>>>(
      W, (long)D * D, D, D, WbT, (long)D * D);
  transpose_cast<<<dim3(D / 32, D / 32, 1), dim3(32, 8), 0, stream>>>(
      Wo, 0, D, D, WobT, 0);

  const float inv_sqrt_d = 0.03125f;  // 1/sqrt(1024)

  for (int i = 0; i < L; ++i) {
    // scores = xb @ xb^T * inv_sqrt_d
    gemm256_bt_scale<<<dim3(S / 256, S / 256, NB), 512, 131072, stream>>>(
        xb, (long)S * D, D, xb, (long)S * D, D,
        scores, (long)S * S, S, inv_sqrt_d, D);
    // softmax rows, in-place bf16 P (lda = 2*S)
    softmax_rows<<<NB * S, 256, 0, stream>>>(scores, S);
    // y = xf + P @ x   (Bt = xbT)
    gemm_pv<EPI_RES_BF16><<<dim3(D / 128, S / 256, NB), 512, 147456, stream>>>(
        (const bf16_t*)scores, (long)2 * S * S, 2 * S, xbT, (long)D * S, S,
        yf, (long)S * D, D, yb, (long)S * D, xf, (long)S * D, nullptr, S);
    // z = yf + relu(yb @ W[i] + b[i])  -> xf, xb
    gemm_pv<EPI_RELU_RES><<<dim3(D / 128, (NB * S) / 256, 1), 512, 147456, stream>>>(
        yb, 0, D, WbT + (size_t)i * D * D, 0, D,
        xf, 0, D, xb, 0, yf, 0, bv + (size_t)i * D, D);
    if (i < L - 1)
      transpose_cast<<<dim3(D / 32, S / 32, NB), dim3(32, 8), 0, stream>>>(
          xf, (long)S * D, S, D, xbT, (long)D * S);
  }

  // out = xb @ Wo + bo
  gemm_pv<EPI_BIAS><<<dim3(D / 128, (NB * S) / 256, 1), 512, 147456, stream>>>(
      xb, 0, D, WobT, 0, D,
      (float*)d_out, 0, D, nullptr, 0, nullptr, 0, bo, D);
}

// Round 8
// 1551.644 us; speedup vs baseline: 1.0035x; 1.0035x over previous
//
#include <hip/hip_runtime.h>
#include <hip/hip_bf16.h>

typedef __bf16 bf16_t;
typedef __bf16 bf16x8_t __attribute__((ext_vector_type(8)));
typedef __bf16 bf16x4_t __attribute__((ext_vector_type(4)));
typedef float f32x4_t __attribute__((ext_vector_type(4)));

#define EPI_RES_BF16 1
#define EPI_RELU_RES 2
#define EPI_BIAS 3

// async 16B global -> LDS (gfx950 global_load_lds_dwordx4)
__device__ __forceinline__ void gload_lds16(const bf16_t* g, bf16_t* l) {
  __builtin_amdgcn_global_load_lds(
      (const __attribute__((address_space(1))) void*)g,
      (__attribute__((address_space(3))) void*)l, 16, 0, 0);
}

__device__ __forceinline__ bf16x8_t ds_read_b128_bf16(unsigned addr) {
  bf16x8_t r;
  asm volatile("ds_read_b128 %0, %1" : "=v"(r) : "v"(addr));
  return r;
}

#define WAIT_VM(n) asm volatile("s_waitcnt vmcnt(" #n ")" ::: "memory")
#define WAIT_LGKM(n) asm volatile("s_waitcnt lgkmcnt(" #n ")" ::: "memory")
#define SCHED_FENCE __builtin_amdgcn_sched_barrier(0)

// Pin occupancy explicitly: 512-thread wg, EXACTLY 2 waves/EU (1 wg/CU, which
// the 128-144 KiB LDS forces anyway) -> unified VGPR budget 512/2 = 256/lane.
// __launch_bounds__(512,2) was ignored by this toolchain (VGPR stayed capped
// at 128 and acc spilled to scratch: 905 MB WRITE_SIZE, 265us dispatches).
#define OCC_ATTR __attribute__((amdgpu_flat_work_group_size(512, 512), amdgpu_waves_per_eu(2, 2)))

// ===========================================================================
// 256x256 merged-phase bf16 GEMM (scores): C = alpha * A @ Bt^T.
// 512 thr = 8 waves (2M x 4N), per-wave 128x64, BK=64 as 2 chunk-phases of 32.
// Chunk ring: 4 slots/operand (16 KiB each), staged 3 chunks ahead,
// counted vmcnt(8); per phase 12 ds_read + 32 MFMA with counted-lgkm split.
// ===========================================================================
__global__ OCC_ATTR void gemm256_bt_scale(
    const bf16_t* __restrict__ A, long aBatch, int lda,
    const bf16_t* __restrict__ Bt, long bBatch, int ldb,
    float* __restrict__ C, long cBatch, int ldc,
    float alpha, int K)
{
  extern __shared__ char smem[];
  typedef __attribute__((address_space(3))) char lds_char_t;
  const unsigned ldsBase = (unsigned)(size_t)(lds_char_t*)smem;

  const unsigned gx = gridDim.x, gy = gridDim.y;
  const unsigned nwg = gx * gy * gridDim.z;
  const unsigned lin = blockIdx.x + gx * (blockIdx.y + gy * blockIdx.z);
  const unsigned swz = (lin & 7u) * (nwg >> 3) + (lin >> 3);
  const unsigned bx = swz % gx;
  const unsigned tq = swz / gx;
  const unsigned by = tq % gy;
  const unsigned bz = tq / gy;

  A += (long)bz * aBatch;
  Bt += (long)bz * bBatch;
  C += (long)bz * cBatch;

  const int tid = threadIdx.x, wid = tid >> 6, lane = tid & 63;
  const int wm = wid >> 2, wn = wid & 3;     // 2M x 4N waves; per-wave 128x64
  const int lr = lane & 15, lh = lane >> 4;
  const int sw2 = ((lr >> 3) & 1) << 1;
  const unsigned cbyte = (unsigned)((lh ^ sw2) << 4);

  const int gsw = ((lane >> 5) & 1) << 1;
  const int gcol = ((lane & 3) ^ gsw) << 3;
  const int grow = wid * 16 + (lane >> 2);
  const bf16_t* Ag = A + (long)(by * 256 + grow) * lda + gcol;
  const bf16_t* Bg = Bt + (long)(bx * 256 + grow) * ldb + gcol;

  // chunk n covers k = n*32..n*32+31; slot = n & 3 (A at slot*16K, B at +64K)
#define STAGE_CH(N_, SLOT) do { \
    const bf16_t* _sa = Ag + (long)(N_) * 32; \
    bf16_t* _da = (bf16_t*)(smem + (SLOT) * 16384 + wid * 1024); \
    gload_lds16(_sa, _da); \
    gload_lds16(_sa + (long)128 * lda, (bf16_t*)((char*)_da + 8192)); \
    const bf16_t* _sb = Bg + (long)(N_) * 32; \
    bf16_t* _db = (bf16_t*)(smem + 65536 + (SLOT) * 16384 + wid * 1024); \
    gload_lds16(_sb, _db); \
    gload_lds16(_sb + (long)128 * ldb, (bf16_t*)((char*)_db + 8192)); \
  } while (0)

  const unsigned aAddr = ldsBase + (unsigned)((wm * 128 + lr) * 64) + cbyte;
  const unsigned bAddr = ldsBase + 65536u + (unsigned)((wn * 64 + lr) * 64) + cbyte;

  bf16x8_t aF[4], aG[4], bF[4];
  f32x4_t acc[8][4] = {};

#define MF16(AB, AF) do { \
    __builtin_amdgcn_s_setprio(1); \
    _Pragma("unroll") for (int _n = 0; _n < 4; ++_n) \
      _Pragma("unroll") for (int _m = 0; _m < 4; ++_m) \
        acc[(AB) + _m][_n] = __builtin_amdgcn_mfma_f32_16x16x32_bf16( \
            AF[_m], bF[_n], acc[(AB) + _m][_n], 0, 0, 0); \
    __builtin_amdgcn_s_setprio(0); \
  } while (0)

#define SPHASE(SLOT, STAGE_STMT, VM_STMT) do { \
    const unsigned _sb = (unsigned)(SLOT) * 16384u; \
    _Pragma("unroll") for (int _m = 0; _m < 4; ++_m) \
      aF[_m] = ds_read_b128_bf16(aAddr + _sb + _m * 1024u); \
    _Pragma("unroll") for (int _n = 0; _n < 4; ++_n) \
      bF[_n] = ds_read_b128_bf16(bAddr + _sb + _n * 1024u); \
    _Pragma("unroll") for (int _m = 0; _m < 4; ++_m) \
      aG[_m] = ds_read_b128_bf16(aAddr + _sb + 4096u + _m * 1024u); \
    STAGE_STMT; \
    VM_STMT; \
    __builtin_amdgcn_s_barrier(); \
    WAIT_LGKM(4); \
    SCHED_FENCE; \
    MF16(0, aF); \
    WAIT_LGKM(0); \
    SCHED_FENCE; \
    MF16(4, aG); \
    __builtin_amdgcn_s_barrier(); \
    SCHED_FENCE; \
  } while (0)

  const int nt = K >> 6;  // >= 2

  // prologue: chunks 0,1,2 into slots 0,1,2; retire chunk 0 (vm in-order)
  STAGE_CH(0, 0); STAGE_CH(1, 1); STAGE_CH(2, 2);
  WAIT_VM(8);
  __builtin_amdgcn_s_barrier();
  SCHED_FENCE;

  int bufc = 0;
  for (int kt = 0; kt < nt; ++kt, bufc ^= 1) {
    const int s0 = bufc * 2, s1 = s0 + 1;
    const int sA = ((bufc ^ 1) << 1) + 1;  // slot for chunk 2kt+3
    // phase n=2kt (H0): stage chunk 2kt+3; retire chunk 2kt+1
    if (kt + 1 < nt) {
      SPHASE(s0, STAGE_CH(2 * kt + 3, sA), WAIT_VM(8));
    } else {
      SPHASE(s0, (void)0, WAIT_VM(0));
    }
    // phase n=2kt+1 (H1): stage chunk 2kt+4 into s0; retire chunk 2kt+2
    if (kt + 2 < nt) {
      SPHASE(s1, STAGE_CH(2 * kt + 4, s0), WAIT_VM(8));
    } else if (kt + 1 < nt) {
      SPHASE(s1, (void)0, WAIT_VM(4));
    } else {
      SPHASE(s1, (void)0, WAIT_VM(0));
    }
  }

  const long r0 = (long)by * 256 + wm * 128;
  const int c0 = bx * 256 + wn * 64;
#pragma unroll
  for (int m = 0; m < 8; ++m)
#pragma unroll
    for (int n = 0; n < 4; ++n)
#pragma unroll
      for (int r = 0; r < 4; ++r)
        C[(r0 + m * 16 + lh * 4 + r) * ldc + c0 + n * 16 + lr] = acc[m][n][r] * alpha;

#undef SPHASE
#undef MF16
#undef STAGE_CH
}

// ===========================================================================
// 256x128 merged-phase bf16 GEMM (PV/FFN/proj): one barrier-pair per K-tile.
// 512 thr = 8 waves (4M x 2N), per-wave 64x64, BK=64. Ring-3 K-tile buffers
// (A 3x32 KiB + B 3x16 KiB = 144 KiB LDS). Per K-tile: 16 ds_read + 32 MFMA,
// counted-lgkm split, counted vmcnt(6).
// ===========================================================================
template <int EPI>
__global__ OCC_ATTR void gemm_pv(
    const bf16_t* __restrict__ A, long aBatch, int lda,
    const bf16_t* __restrict__ Bt, long bBatch, int ldb,
    float* __restrict__ Cf, long cfBatch, int ldc,
    bf16_t* __restrict__ Cb, long cbBatch,
    const float* __restrict__ Res, long resBatch,
    const float* __restrict__ bias, int K)
{
  extern __shared__ char smem[];
  typedef __attribute__((address_space(3))) char lds_char_t;
  const unsigned ldsBase = (unsigned)(size_t)(lds_char_t*)smem;

  const unsigned gx = gridDim.x, gy = gridDim.y;
  const unsigned nwg = gx * gy * gridDim.z;
  const unsigned lin = blockIdx.x + gx * (blockIdx.y + gy * blockIdx.z);
  const unsigned swz = (lin & 7u) * (nwg >> 3) + (lin >> 3);
  const unsigned bx = swz % gx;
  const unsigned tq = swz / gx;
  const unsigned by = tq % gy;
  const unsigned bz = tq / gy;

  A += (long)bz * aBatch;
  Bt += (long)bz * bBatch;
  Cf += (long)bz * cfBatch;
  if (Cb) Cb += (long)bz * cbBatch;
  if (Res) Res += (long)bz * resBatch;

  const int tid = threadIdx.x, wid = tid >> 6, lane = tid & 63;
  const int wm = wid >> 1, wn = wid & 1;     // 4M x 2N waves; per-wave 64x64
  const int lr = lane & 15, lh = lane >> 4;
  const int sw2 = ((lr >> 3) & 1) << 1;
  const unsigned cbyte = (unsigned)((lh ^ sw2) << 4);

  const int gsw = ((lane >> 5) & 1) << 1;
  const int gcol = ((lane & 3) ^ gsw) << 3;
  const int grow = wid * 16 + (lane >> 2);
  const bf16_t* Ag = A + (long)(by * 256 + grow) * lda + gcol;
  const bf16_t* Bg = Bt + (long)(bx * 128 + grow) * ldb + gcol;

  // LDS: A at so*32768 + H*16384 (3 K-tile slots); B at 98304 + so*16384 + H*8192
#define STAGE_KT(KT, SO) do { \
    const bf16_t* _sa = Ag + (long)(KT) * 64; \
    char* _da = smem + (SO) * 32768 + wid * 1024; \
    gload_lds16(_sa, (bf16_t*)_da); \
    gload_lds16(_sa + (long)128 * lda, (bf16_t*)(_da + 8192)); \
    gload_lds16(_sa + 32, (bf16_t*)(_da + 16384)); \
    gload_lds16(_sa + (long)128 * lda + 32, (bf16_t*)(_da + 16384 + 8192)); \
    const bf16_t* _sb = Bg + (long)(KT) * 64; \
    char* _db = smem + 98304 + (SO) * 16384 + wid * 1024; \
    gload_lds16(_sb, (bf16_t*)_db); \
    gload_lds16(_sb + 32, (bf16_t*)(_db + 8192)); \
  } while (0)

  const unsigned aAddr = ldsBase + (unsigned)((wm * 64 + lr) * 64) + cbyte;
  const unsigned bAddr = ldsBase + 98304u + (unsigned)((wn * 64 + lr) * 64) + cbyte;

  bf16x8_t aF[4], aG[4], bF[4], bG[4];
  f32x4_t acc[4][4] = {};

#define PPHASE(SO, STAGE_STMT, VM_STMT) do { \
    const unsigned _ab = aAddr + (unsigned)(SO) * 32768u; \
    const unsigned _bb = bAddr + (unsigned)(SO) * 16384u; \
    _Pragma("unroll") for (int _m = 0; _m < 4; ++_m) \
      aF[_m] = ds_read_b128_bf16(_ab + _m * 1024u); \
    _Pragma("unroll") for (int _n = 0; _n < 4; ++_n) \
      bF[_n] = ds_read_b128_bf16(_bb + _n * 1024u); \
    _Pragma("unroll") for (int _m = 0; _m < 4; ++_m) \
      aG[_m] = ds_read_b128_bf16(_ab + 16384u + _m * 1024u); \
    _Pragma("unroll") for (int _n = 0; _n < 4; ++_n) \
      bG[_n] = ds_read_b128_bf16(_bb + 8192u + _n * 1024u); \
    STAGE_STMT; \
    VM_STMT; \
    __builtin_amdgcn_s_barrier(); \
    WAIT_LGKM(8); \
    SCHED_FENCE; \
    __builtin_amdgcn_s_setprio(1); \
    _Pragma("unroll") for (int _n = 0; _n < 4; ++_n) \
      _Pragma("unroll") for (int _m = 0; _m < 4; ++_m) \
        acc[_m][_n] = __builtin_amdgcn_mfma_f32_16x16x32_bf16(aF[_m], bF[_n], acc[_m][_n], 0, 0, 0); \
    __builtin_amdgcn_s_setprio(0); \
    WAIT_LGKM(0); \
    SCHED_FENCE; \
    __builtin_amdgcn_s_setprio(1); \
    _Pragma("unroll") for (int _n = 0; _n < 4; ++_n) \
      _Pragma("unroll") for (int _m = 0; _m < 4; ++_m) \
        acc[_m][_n] = __builtin_amdgcn_mfma_f32_16x16x32_bf16(aG[_m], bG[_n], acc[_m][_n], 0, 0, 0); \
    __builtin_amdgcn_s_setprio(0); \
    __builtin_amdgcn_s_barrier(); \
    SCHED_FENCE; \
  } while (0)

  const int nt = K >> 6;  // >= 3

  STAGE_KT(0, 0); STAGE_KT(1, 1);   // 12 loads; retire K-tile 0
  WAIT_VM(6);
  __builtin_amdgcn_s_barrier();
  SCHED_FENCE;

  int so = 0;
  for (int kt = 0; kt < nt; ++kt) {
    int sn = so + 2; if (sn >= 3) sn -= 3;
    if (kt + 2 < nt) {
      PPHASE(so, STAGE_KT(kt + 2, sn), WAIT_VM(6));
    } else {
      PPHASE(so, (void)0, WAIT_VM(0));
    }
    so += 1; if (so >= 3) so = 0;
  }

  // epilogue: C/D layout col = lane&15, row = (lane>>4)*4 + reg
  const long r0 = (long)by * 256 + wm * 64;
  const int c0 = bx * 128 + wn * 64;
#pragma unroll
  for (int m = 0; m < 4; ++m) {
#pragma unroll
    for (int n = 0; n < 4; ++n) {
#pragma unroll
      for (int r = 0; r < 4; ++r) {
        const long row = r0 + m * 16 + lh * 4 + r;
        const int col = c0 + n * 16 + lr;
        const float v = acc[m][n][r];
        if constexpr (EPI == EPI_BIAS) {
          Cf[row * ldc + col] = v + bias[col];
        } else if constexpr (EPI == EPI_RES_BF16) {
          const float o = Res[row * ldc + col] + v;
          Cf[row * ldc + col] = o;
          Cb[row * ldc + col] = (bf16_t)o;
        } else {  // EPI_RELU_RES
          float t = v + bias[col];
          t = t > 0.f ? t : 0.f;
          const float o = Res[row * ldc + col] + t;
          Cf[row * ldc + col] = o;
          Cb[row * ldc + col] = (bf16_t)o;
        }
      }
    }
  }
#undef PPHASE
#undef STAGE_KT
}

// ---------------------------------------------------------------------------
// Row softmax over S f32 values, in-place bf16 writeback (rows at f32 stride,
// so P is later read with lda = 2*S bf16 elems). One block (256 thr) per row.
// ---------------------------------------------------------------------------
__global__ __launch_bounds__(256) void softmax_rows(float* __restrict__ scores, int S)
{
  const long row = blockIdx.x;
  float* p = scores + row * (long)S;
  const int t = threadIdx.x;
  const int lane = t & 63, wave = t >> 6;

  float4 v0 = ((const float4*)p)[t * 2];
  float4 v1 = ((const float4*)p)[t * 2 + 1];
  float e[8] = {v0.x, v0.y, v0.z, v0.w, v1.x, v1.y, v1.z, v1.w};

  float m = e[0];
#pragma unroll
  for (int j = 1; j < 8; ++j) m = fmaxf(m, e[j]);
#pragma unroll
  for (int off = 32; off >= 1; off >>= 1) m = fmaxf(m, __shfl_xor(m, off));

  __shared__ float redm[4], reds[4];
  if (lane == 0) redm[wave] = m;
  __syncthreads();
  m = fmaxf(fmaxf(redm[0], redm[1]), fmaxf(redm[2], redm[3]));

  float s = 0.f;
#pragma unroll
  for (int j = 0; j < 8; ++j) { e[j] = __expf(e[j] - m); s += e[j]; }
#pragma unroll
  for (int off = 32; off >= 1; off >>= 1) s += __shfl_xor(s, off);
  if (lane == 0) reds[wave] = s;
  __syncthreads();
  s = reds[0] + reds[1] + reds[2] + reds[3];
  const float inv = 1.f / s;

  bf16x8_t ob;
#pragma unroll
  for (int j = 0; j < 8; ++j) ob[j] = (bf16_t)(e[j] * inv);
  ((bf16x8_t*)p)[t] = ob;
}

// ---------------------------------------------------------------------------
__global__ void cast_copy(const float* __restrict__ in, float* __restrict__ outf,
                          bf16_t* __restrict__ outb, long n4)
{
  long i = (long)blockIdx.x * blockDim.x + threadIdx.x;
  const long stride = (long)gridDim.x * blockDim.x;
  for (; i < n4; i += stride) {
    float4 v = ((const float4*)in)[i];
    ((float4*)outf)[i] = v;
    bf16x4_t bv;
    bv[0] = (bf16_t)v.x; bv[1] = (bf16_t)v.y; bv[2] = (bf16_t)v.z; bv[3] = (bf16_t)v.w;
    ((bf16x4_t*)outb)[i] = bv;
  }
}

// ---------------------------------------------------------------------------
__global__ void transpose_cast(const float* __restrict__ in, long inBatch, int R, int C,
                               bf16_t* __restrict__ out, long outBatch)
{
  __shared__ float tile[32][33];
  const float* src = in + (long)blockIdx.z * inBatch;
  bf16_t* dst = out + (long)blockIdx.z * outBatch;
  const int c0 = blockIdx.x * 32, r0 = blockIdx.y * 32;
  const int tx = threadIdx.x, ty = threadIdx.y;
#pragma unroll
  for (int i = 0; i < 32; i += 8) tile[ty + i][tx] = src[(long)(r0 + ty + i) * C + (c0 + tx)];
  __syncthreads();
#pragma unroll
  for (int i = 0; i < 32; i += 8)
    dst[(long)(c0 + ty + i) * R + (r0 + tx)] = (bf16_t)tile[tx][ty + i];
}

// ---------------------------------------------------------------------------
extern "C" void kernel_launch(void* const* d_in, const int* in_sizes, int n_in,
                              void* d_out, int out_size, void* d_ws, size_t ws_size,
                              hipStream_t stream)
{
  constexpr int L = 4, NB = 4, S = 2048, D = 1024;
  const float* x  = (const float*)d_in[0];
  const float* W  = (const float*)d_in[1];
  const float* bv = (const float*)d_in[2];
  const float* Wo = (const float*)d_in[3];
  const float* bo = (const float*)d_in[4];

  char* ws = (char*)d_ws;
  size_t off = 0;
  float* scores = (float*)(ws + off); off += (size_t)NB * S * S * 4;
  float* xf = (float*)(ws + off); off += (size_t)NB * S * D * 4;
  float* yf = (float*)(ws + off); off += (size_t)NB * S * D * 4;
  bf16_t* xb  = (bf16_t*)(ws + off); off += (size_t)NB * S * D * 2;
  bf16_t* xbT = (bf16_t*)(ws + off); off += (size_t)NB * S * D * 2;
  bf16_t* yb  = (bf16_t*)(ws + off); off += (size_t)NB * S * D * 2;
  bf16_t* WbT  = (bf16_t*)(ws + off); off += (size_t)L * D * D * 2;
  bf16_t* WobT = (bf16_t*)(ws + off); off += (size_t)D * D * 2;

  hipFuncSetAttribute((const void*)gemm256_bt_scale,
                      hipFuncAttributeMaxDynamicSharedMemorySize, 131072);
  hipFuncSetAttribute((const void*)gemm_pv<EPI_RES_BF16>,
                      hipFuncAttributeMaxDynamicSharedMemorySize, 147456);
  hipFuncSetAttribute((const void*)gemm_pv<EPI_RELU_RES>,
                      hipFuncAttributeMaxDynamicSharedMemorySize, 147456);
  hipFuncSetAttribute((const void*)gemm_pv<EPI_BIAS>,
                      hipFuncAttributeMaxDynamicSharedMemorySize, 147456);

  const long n4 = (long)NB * S * D / 4;
  cast_copy<<<2048, 256, 0, stream>>>(x, xf, xb, n4);
  transpose_cast<<<dim3(D / 32, S / 32, NB), dim3(32, 8), 0, stream>>>(
      x, (long)S * D, S, D, xbT, (long)D * S);
  transpose_cast<<<dim3(D / 32, D / 32, L), dim3(32, 8), 0, stream>>>(
      W, (long)D * D, D, D, WbT, (long)D * D);
  transpose_cast<<<dim3(D / 32, D / 32, 1), dim3(32, 8), 0, stream>>>(
      Wo, 0, D, D, WobT, 0);

  const float inv_sqrt_d = 0.03125f;  // 1/sqrt(1024)

  for (int i = 0; i < L; ++i) {
    // scores = xb @ xb^T * inv_sqrt_d
    gemm256_bt_scale<<<dim3(S / 256, S / 256, NB), 512, 131072, stream>>>(
        xb, (long)S * D, D, xb, (long)S * D, D,
        scores, (long)S * S, S, inv_sqrt_d, D);
    // softmax rows, in-place bf16 P (lda = 2*S)
    softmax_rows<<<NB * S, 256, 0, stream>>>(scores, S);
    // y = xf + P @ x   (Bt = xbT)
    gemm_pv<EPI_RES_BF16><<<dim3(D / 128, S / 256, NB), 512, 147456, stream>>>(
        (const bf16_t*)scores, (long)2 * S * S, 2 * S, xbT, (long)D * S, S,
        yf, (long)S * D, D, yb, (long)S * D, xf, (long)S * D, nullptr, S);
    // z = yf + relu(yb @ W[i] + b[i])  -> xf, xb
    gemm_pv<EPI_RELU_RES><<<dim3(D / 128, (NB * S) / 256, 1), 512, 147456, stream>>>(
        yb, 0, D, WbT + (size_t)i * D * D, 0, D,
        xf, 0, D, xb, 0, yf, 0, bv + (size_t)i * D, D);
    if (i < L - 1)
      transpose_cast<<<dim3(D / 32, S / 32, NB), dim3(32, 8), 0, stream>>>(
          xf, (long)S * D, S, D, xbT, (long)D * S);
  }

  // out = xb @ Wo + bo
  gemm_pv<EPI_BIAS><<<dim3(D / 128, (NB * S) / 256, 1), 512, 147456, stream>>>(
      xb, 0, D, WobT, 0, D,
      (float*)d_out, 0, D, nullptr, 0, nullptr, 0, bo, D);
}

// Round 9
// 667.453 us; speedup vs baseline: 2.3328x; 2.3247x over previous
//
#include <hip/hip_runtime.h>
#include <hip/hip_bf16.h>

typedef __bf16 bf16_t;
typedef __bf16 bf16x8_t __attribute__((ext_vector_type(8)));
typedef __bf16 bf16x4_t __attribute__((ext_vector_type(4)));
typedef float f32x4_t __attribute__((ext_vector_type(4)));

#define EPI_RES_BF16 1
#define EPI_RELU_RES 2
#define EPI_BIAS 3

// async 16B global -> LDS (gfx950 global_load_lds_dwordx4)
__device__ __forceinline__ void gload_lds16(const bf16_t* g, bf16_t* l) {
  __builtin_amdgcn_global_load_lds(
      (const __attribute__((address_space(1))) void*)g,
      (__attribute__((address_space(3))) void*)l, 16, 0, 0);
}

__device__ __forceinline__ bf16x8_t ds_read_b128_bf16(unsigned addr) {
  bf16x8_t r;
  asm volatile("ds_read_b128 %0, %1" : "=v"(r) : "v"(addr));
  return r;
}

#define WAIT_VM(n) asm volatile("s_waitcnt vmcnt(" #n ")" ::: "memory")
#define WAIT_LGKM(n) asm volatile("s_waitcnt lgkmcnt(" #n ")" ::: "memory")
#define SCHED_FENCE __builtin_amdgcn_sched_barrier(0)

// ===========================================================================
// 256x256 8-phase bf16 GEMM (scores): C = alpha * A @ Bt^T, K multiple of 64,
// grid (N/256, M/256, batch), 512 threads = 8 waves (2M x 4N), BK=64.
// ROUND-5 BUILD VERBATIM (measured ~62us @ our shape, no spill).
// ===========================================================================
__global__ __launch_bounds__(512) void gemm256_bt_scale(
    const bf16_t* __restrict__ A, long aBatch, int lda,
    const bf16_t* __restrict__ Bt, long bBatch, int ldb,
    float* __restrict__ C, long cBatch, int ldc,
    float alpha, int K)
{
  extern __shared__ char smem[];
  typedef __attribute__((address_space(3))) char lds_char_t;
  const unsigned ldsBase = (unsigned)(size_t)(lds_char_t*)smem;

  const unsigned gx = gridDim.x, gy = gridDim.y;
  const unsigned nwg = gx * gy * gridDim.z;
  const unsigned lin = blockIdx.x + gx * (blockIdx.y + gy * blockIdx.z);
  const unsigned swz = (lin & 7u) * (nwg >> 3) + (lin >> 3);
  const unsigned bx = swz % gx;
  const unsigned tq = swz / gx;
  const unsigned by = tq % gy;
  const unsigned bz = tq / gy;

  A += (long)bz * aBatch;
  Bt += (long)bz * bBatch;
  C += (long)bz * cBatch;

  const int tid = threadIdx.x, wid = tid >> 6, lane = tid & 63;
  const int wm = wid >> 2, wn = wid & 3;     // 2M x 4N waves; per-wave out 128x64
  const int lr = lane & 15, lh = lane >> 4;
  const int sw2 = ((lr >> 3) & 1) << 1;
  const unsigned cbyte = (unsigned)((lh ^ sw2) << 4);

  const int gsw = ((lane >> 5) & 1) << 1;
  const int gcol = ((lane & 3) ^ gsw) << 3;
  const int grow = wid * 16 + (lane >> 2);
  const bf16_t* Ag = A + (long)(by * 256 + grow) * lda + gcol;
  const bf16_t* Bg = Bt + (long)(bx * 256 + grow) * ldb + gcol;

#define STAGE_A(KT, H, B_) do { \
    const bf16_t* _s = Ag + (long)(KT) * 64 + (H) * 32; \
    bf16_t* _d = (bf16_t*)(smem + (B_) * 32768 + (H) * 16384 + wid * 1024); \
    gload_lds16(_s, _d); \
    gload_lds16(_s + (long)128 * lda, (bf16_t*)((char*)_d + 8192)); \
  } while (0)
#define STAGE_B(KT, H, B_) do { \
    const bf16_t* _s = Bg + (long)(KT) * 64 + (H) * 32; \
    bf16_t* _d = (bf16_t*)(smem + 65536 + (B_) * 32768 + (H) * 16384 + wid * 1024); \
    gload_lds16(_s, _d); \
    gload_lds16(_s + (long)128 * ldb, (bf16_t*)((char*)_d + 8192)); \
  } while (0)

  const unsigned aAddr = ldsBase + (unsigned)((wm * 128 + lr) * 64) + cbyte;
  const unsigned bAddr = ldsBase + 65536u + (unsigned)((wn * 64 + lr) * 64) + cbyte;

  bf16x8_t aF[4], bF[4];
  f32x4_t acc[8][4] = {};

#define MFMA16(MH) do { \
    __builtin_amdgcn_s_setprio(1); \
    _Pragma("unroll") for (int _n = 0; _n < 4; ++_n) \
      _Pragma("unroll") for (int _m = 0; _m < 4; ++_m) \
        acc[(MH) * 4 + _m][_n] = __builtin_amdgcn_mfma_f32_16x16x32_bf16( \
            aF[_m], bF[_n], acc[(MH) * 4 + _m][_n], 0, 0, 0); \
    __builtin_amdgcn_s_setprio(0); \
  } while (0)

#define PHASE(MH, H, B_, STAGE_STMT, VM_STMT) do { \
    _Pragma("unroll") for (int _m = 0; _m < 4; ++_m) \
      aF[_m] = ds_read_b128_bf16(aAddr + (unsigned)(B_)*32768u + (H)*16384u + ((MH)*4 + _m)*1024u); \
    if ((MH) == 0) { \
      _Pragma("unroll") for (int _n = 0; _n < 4; ++_n) \
        bF[_n] = ds_read_b128_bf16(bAddr + (unsigned)(B_)*32768u + (H)*16384u + _n*1024u); \
    } \
    STAGE_STMT; \
    VM_STMT; \
    __builtin_amdgcn_s_barrier(); \
    WAIT_LGKM(0); \
    SCHED_FENCE; \
    MFMA16(MH); \
    __builtin_amdgcn_s_barrier(); \
    SCHED_FENCE; \
  } while (0)

  const int nt = K >> 6;  // >= 3

  STAGE_A(0, 0, 0); STAGE_B(0, 0, 0); STAGE_A(0, 1, 0); STAGE_B(0, 1, 0);
  STAGE_A(1, 0, 1); STAGE_B(1, 0, 1);
  WAIT_VM(8);
  __builtin_amdgcn_s_barrier();
  SCHED_FENCE;

  int bufc = 0;
  for (int kt = 0; kt < nt; ++kt, bufc ^= 1) {
    const int bo = bufc ^ 1;
    const bool st12 = (kt + 1 < nt);
    const bool st34 = (kt + 2 < nt);
    PHASE(0, 0, bufc, if (st12) STAGE_A(kt + 1, 1, bo), );
    PHASE(1, 0, bufc, if (st12) STAGE_B(kt + 1, 1, bo),
          if (kt == nt - 1) { WAIT_VM(0); } else { WAIT_VM(8); });
    PHASE(0, 1, bufc, if (st34) STAGE_A(kt + 2, 0, bufc), );
    PHASE(1, 1, bufc, if (st34) STAGE_B(kt + 2, 0, bufc),
          if (kt < nt - 2) { WAIT_VM(8); } else { WAIT_VM(4); });
  }

  const long r0 = (long)by * 256 + wm * 128;
  const int c0 = bx * 256 + wn * 64;
#pragma unroll
  for (int m = 0; m < 8; ++m)
#pragma unroll
    for (int n = 0; n < 4; ++n)
#pragma unroll
      for (int r = 0; r < 4; ++r)
        C[(r0 + m * 16 + lh * 4 + r) * ldc + c0 + n * 16 + lr] = acc[m][n][r] * alpha;

#undef PHASE
#undef MFMA16
#undef STAGE_A
#undef STAGE_B
}

// ===========================================================================
// 128x128 ring-3 bf16 GEMM (PV/FFN/proj): designed for <=128 VGPR (no spill)
// and 3 wg/CU (48 KiB static LDS) so independent workgroups hide each
// other's barrier/latency stalls (m114 overlap) while counted vmcnt keeps
// loads in flight. 256 thr = 4 waves (2M x 2N), per-wave 64x64, BK=32.
// Ring slots s=0..2: A chunk 128x32 @ s*16K, B chunk @ s*16K+8K.
// Step kt: STAGE(kt+2) -> ds_read(slot kt%3) -> vmcnt(4) (retire chunk kt+1,
// one step early) -> barrier -> lgkm0 -> 16 MFMA -> barrier.
// Regs: acc 64 + frags 32 + addr ~20 = ~116 < 128.
// ===========================================================================
template <int EPI>
__global__ __launch_bounds__(256) void gemm_r3(
    const bf16_t* __restrict__ A, long aBatch, int lda,
    const bf16_t* __restrict__ Bt, long bBatch, int ldb,
    float* __restrict__ Cf, long cfBatch, int ldc,
    bf16_t* __restrict__ Cb, long cbBatch,
    const float* __restrict__ Res, long resBatch,
    const float* __restrict__ bias, int K)
{
  __shared__ char smem[49152];
  typedef __attribute__((address_space(3))) char lds_char_t;
  const unsigned ldsBase = (unsigned)(size_t)(lds_char_t*)smem;

  const unsigned gx = gridDim.x, gy = gridDim.y;
  const unsigned nwg = gx * gy * gridDim.z;
  const unsigned lin = blockIdx.x + gx * (blockIdx.y + gy * blockIdx.z);
  const unsigned swz = (lin & 7u) * (nwg >> 3) + (lin >> 3);
  const unsigned bx = swz % gx;
  const unsigned tq = swz / gx;
  const unsigned by = tq % gy;
  const unsigned bz = tq / gy;

  A += (long)bz * aBatch;
  Bt += (long)bz * bBatch;
  Cf += (long)bz * cfBatch;
  if (Cb) Cb += (long)bz * cbBatch;
  if (Res) Res += (long)bz * resBatch;

  const int tid = threadIdx.x, wid = tid >> 6, lane = tid & 63;
  const int wm = wid >> 1, wn = wid & 1;     // 2M x 2N waves; per-wave 64x64
  const int lr = lane & 15, lh = lane >> 4;
  const int sw2 = ((lr >> 3) & 1) << 1;
  const unsigned cbyte = (unsigned)((lh ^ sw2) << 4);   // XOR slot-bit1 with row-bit3

  // staging: wave w covers rows w*16 + lane/4 (issue 2: +64); source col
  // pre-swizzled by row bit3 (= lane bit5) so LDS dest stays linear (rule 21)
  const int gsw = ((lane >> 5) & 1) << 1;
  const int gcol = ((lane & 3) ^ gsw) << 3;
  const int grow = wid * 16 + (lane >> 2);
  const bf16_t* Ag = A + (long)(by * 128 + grow) * lda + gcol;
  const bf16_t* Bg = Bt + (long)(bx * 128 + grow) * ldb + gcol;

  // chunk kt -> slot kt%3: A 8KB @ slot*16K, B 8KB @ slot*16K + 8K
#define STAGE(KT, SO) do { \
    const bf16_t* _sa = Ag + (long)(KT) * 32; \
    bf16_t* _da = (bf16_t*)(smem + (SO) * 16384 + wid * 1024); \
    gload_lds16(_sa, _da); \
    gload_lds16(_sa + (long)64 * lda, (bf16_t*)((char*)_da + 4096)); \
    const bf16_t* _sb = Bg + (long)(KT) * 32; \
    bf16_t* _db = (bf16_t*)(smem + (SO) * 16384 + 8192 + wid * 1024); \
    gload_lds16(_sb, _db); \
    gload_lds16(_sb + (long)64 * ldb, (bf16_t*)((char*)_db + 4096)); \
  } while (0)

  const unsigned aAddr = ldsBase + (unsigned)((wm * 64 + lr) * 64) + cbyte;
  const unsigned bAddr = ldsBase + 8192u + (unsigned)((wn * 64 + lr) * 64) + cbyte;

  bf16x8_t aF[4], bF[4];
  f32x4_t acc[4][4] = {};

#define RSTEP(SO, STAGE_STMT, VM_STMT) do { \
    STAGE_STMT; \
    const unsigned _ab = aAddr + (unsigned)(SO) * 16384u; \
    const unsigned _bb = bAddr + (unsigned)(SO) * 16384u; \
    _Pragma("unroll") for (int _m = 0; _m < 4; ++_m) \
      aF[_m] = ds_read_b128_bf16(_ab + _m * 1024u); \
    _Pragma("unroll") for (int _n = 0; _n < 4; ++_n) \
      bF[_n] = ds_read_b128_bf16(_bb + _n * 1024u); \
    VM_STMT; \
    __builtin_amdgcn_s_barrier(); \
    WAIT_LGKM(0); \
    SCHED_FENCE; \
    __builtin_amdgcn_s_setprio(1); \
    _Pragma("unroll") for (int _n = 0; _n < 4; ++_n) \
      _Pragma("unroll") for (int _m = 0; _m < 4; ++_m) \
        acc[_m][_n] = __builtin_amdgcn_mfma_f32_16x16x32_bf16(aF[_m], bF[_n], acc[_m][_n], 0, 0, 0); \
    __builtin_amdgcn_s_setprio(0); \
    __builtin_amdgcn_s_barrier(); \
    SCHED_FENCE; \
  } while (0)

  const int nt = K >> 5;  // K/32 >= 3 for all our shapes

  // prologue: chunks 0,1 -> slots 0,1; retire chunk 0 (vmcnt: 8 outstanding -> 4)
  STAGE(0, 0); STAGE(1, 1);
  WAIT_VM(4);
  __builtin_amdgcn_s_barrier();
  SCHED_FENCE;

  int so = 0;
  for (int kt = 0; kt < nt; ++kt) {
    int sn = so + 2; if (sn >= 3) sn -= 3;
    if (kt + 2 < nt) {
      RSTEP(so, STAGE(kt + 2, sn), WAIT_VM(4));  // retire chunk kt+1
    } else {
      RSTEP(so, (void)0, WAIT_VM(0));            // tail drain
    }
    so += 1; if (so >= 3) so = 0;
  }

  // epilogue: C/D layout col = lane&15, row = (lane>>4)*4 + reg
  const long r0 = (long)by * 128 + wm * 64;
  const int c0 = bx * 128 + wn * 64;
#pragma unroll
  for (int m = 0; m < 4; ++m) {
#pragma unroll
    for (int n = 0; n < 4; ++n) {
#pragma unroll
      for (int r = 0; r < 4; ++r) {
        const long row = r0 + m * 16 + lh * 4 + r;
        const int col = c0 + n * 16 + lr;
        const float v = acc[m][n][r];
        if constexpr (EPI == EPI_BIAS) {
          Cf[row * ldc + col] = v + bias[col];
        } else if constexpr (EPI == EPI_RES_BF16) {
          const float o = Res[row * ldc + col] + v;
          Cf[row * ldc + col] = o;
          Cb[row * ldc + col] = (bf16_t)o;
        } else {  // EPI_RELU_RES
          float t = v + bias[col];
          t = t > 0.f ? t : 0.f;
          const float o = Res[row * ldc + col] + t;
          Cf[row * ldc + col] = o;
          Cb[row * ldc + col] = (bf16_t)o;
        }
      }
    }
  }
#undef RSTEP
#undef STAGE
}

// ---------------------------------------------------------------------------
// Row softmax over S f32 values, in-place bf16 writeback (rows at f32 stride,
// so P is later read with lda = 2*S bf16 elems). One block (256 thr) per row.
// ---------------------------------------------------------------------------
__global__ __launch_bounds__(256) void softmax_rows(float* __restrict__ scores, int S)
{
  const long row = blockIdx.x;
  float* p = scores + row * (long)S;
  const int t = threadIdx.x;
  const int lane = t & 63, wave = t >> 6;

  float4 v0 = ((const float4*)p)[t * 2];
  float4 v1 = ((const float4*)p)[t * 2 + 1];
  float e[8] = {v0.x, v0.y, v0.z, v0.w, v1.x, v1.y, v1.z, v1.w};

  float m = e[0];
#pragma unroll
  for (int j = 1; j < 8; ++j) m = fmaxf(m, e[j]);
#pragma unroll
  for (int off = 32; off >= 1; off >>= 1) m = fmaxf(m, __shfl_xor(m, off));

  __shared__ float redm[4], reds[4];
  if (lane == 0) redm[wave] = m;
  __syncthreads();
  m = fmaxf(fmaxf(redm[0], redm[1]), fmaxf(redm[2], redm[3]));

  float s = 0.f;
#pragma unroll
  for (int j = 0; j < 8; ++j) { e[j] = __expf(e[j] - m); s += e[j]; }
#pragma unroll
  for (int off = 32; off >= 1; off >>= 1) s += __shfl_xor(s, off);
  if (lane == 0) reds[wave] = s;
  __syncthreads();
  s = reds[0] + reds[1] + reds[2] + reds[3];
  const float inv = 1.f / s;

  bf16x8_t ob;
#pragma unroll
  for (int j = 0; j < 8; ++j) ob[j] = (bf16_t)(e[j] * inv);
  ((bf16x8_t*)p)[t] = ob;
}

// ---------------------------------------------------------------------------
__global__ void cast_copy(const float* __restrict__ in, float* __restrict__ outf,
                          bf16_t* __restrict__ outb, long n4)
{
  long i = (long)blockIdx.x * blockDim.x + threadIdx.x;
  const long stride = (long)gridDim.x * blockDim.x;
  for (; i < n4; i += stride) {
    float4 v = ((const float4*)in)[i];
    ((float4*)outf)[i] = v;
    bf16x4_t bv;
    bv[0] = (bf16_t)v.x; bv[1] = (bf16_t)v.y; bv[2] = (bf16_t)v.z; bv[3] = (bf16_t)v.w;
    ((bf16x4_t*)outb)[i] = bv;
  }
}

// ---------------------------------------------------------------------------
__global__ void transpose_cast(const float* __restrict__ in, long inBatch, int R, int C,
                               bf16_t* __restrict__ out, long outBatch)
{
  __shared__ float tile[32][33];
  const float* src = in + (long)blockIdx.z * inBatch;
  bf16_t* dst = out + (long)blockIdx.z * outBatch;
  const int c0 = blockIdx.x * 32, r0 = blockIdx.y * 32;
  const int tx = threadIdx.x, ty = threadIdx.y;
#pragma unroll
  for (int i = 0; i < 32; i += 8) tile[ty + i][tx] = src[(long)(r0 + ty + i) * C + (c0 + tx)];
  __syncthreads();
#pragma unroll
  for (int i = 0; i < 32; i += 8)
    dst[(long)(c0 + ty + i) * R + (r0 + tx)] = (bf16_t)tile[tx][ty + i];
}

// ---------------------------------------------------------------------------
extern "C" void kernel_launch(void* const* d_in, const int* in_sizes, int n_in,
                              void* d_out, int out_size, void* d_ws, size_t ws_size,
                              hipStream_t stream)
{
  constexpr int L = 4, NB = 4, S = 2048, D = 1024;
  const float* x  = (const float*)d_in[0];
  const float* W  = (const float*)d_in[1];
  const float* bv = (const float*)d_in[2];
  const float* Wo = (const float*)d_in[3];
  const float* bo = (const float*)d_in[4];

  char* ws = (char*)d_ws;
  size_t off = 0;
  float* scores = (float*)(ws + off); off += (size_t)NB * S * S * 4;
  float* xf = (float*)(ws + off); off += (size_t)NB * S * D * 4;
  float* yf = (float*)(ws + off); off += (size_t)NB * S * D * 4;
  bf16_t* xb  = (bf16_t*)(ws + off); off += (size_t)NB * S * D * 2;
  bf16_t* xbT = (bf16_t*)(ws + off); off += (size_t)NB * S * D * 2;
  bf16_t* yb  = (bf16_t*)(ws + off); off += (size_t)NB * S * D * 2;
  bf16_t* WbT  = (bf16_t*)(ws + off); off += (size_t)L * D * D * 2;
  bf16_t* WobT = (bf16_t*)(ws + off); off += (size_t)D * D * 2;

  hipFuncSetAttribute((const void*)gemm256_bt_scale,
                      hipFuncAttributeMaxDynamicSharedMemorySize, 131072);

  const long n4 = (long)NB * S * D / 4;
  cast_copy<<<2048, 256, 0, stream>>>(x, xf, xb, n4);
  transpose_cast<<<dim3(D / 32, S / 32, NB), dim3(32, 8), 0, stream>>>(
      x, (long)S * D, S, D, xbT, (long)D * S);
  transpose_cast<<<dim3(D / 32, D / 32, L), dim3(32, 8), 0, stream>>>(
      W, (long)D * D, D, D, WbT, (long)D * D);
  transpose_cast<<<dim3(D / 32, D / 32, 1), dim3(32, 8), 0, stream>>>(
      Wo, 0, D, D, WobT, 0);

  const float inv_sqrt_d = 0.03125f;  // 1/sqrt(1024)

  for (int i = 0; i < L; ++i) {
    // scores = xb @ xb^T * inv_sqrt_d  (round-5 8-phase 256^2 kernel)
    gemm256_bt_scale<<<dim3(S / 256, S / 256, NB), 512, 131072, stream>>>(
        xb, (long)S * D, D, xb, (long)S * D, D,
        scores, (long)S * S, S, inv_sqrt_d, D);
    // softmax rows, in-place bf16 P (lda = 2*S)
    softmax_rows<<<NB * S, 256, 0, stream>>>(scores, S);
    // y = xf + P @ x   (Bt = xbT) — ring-3 128^2, 3 wg/CU
    gemm_r3<EPI_RES_BF16><<<dim3(D / 128, S / 128, NB), 256, 0, stream>>>(
        (const bf16_t*)scores, (long)2 * S * S, 2 * S, xbT, (long)D * S, S,
        yf, (long)S * D, D, yb, (long)S * D, xf, (long)S * D, nullptr, S);
    // z = yf + relu(yb @ W[i] + b[i])  -> xf, xb
    gemm_r3<EPI_RELU_RES><<<dim3(D / 128, (NB * S) / 128, 1), 256, 0, stream>>>(
        yb, 0, D, WbT + (size_t)i * D * D, 0, D,
        xf, 0, D, xb, 0, yf, 0, bv + (size_t)i * D, D);
    if (i < L - 1)
      transpose_cast<<<dim3(D / 32, S / 32, NB), dim3(32, 8), 0, stream>>>(
          xf, (long)S * D, S, D, xbT, (long)D * S);
  }

  // out = xb @ Wo + bo
  gemm_r3<EPI_BIAS><<<dim3(D / 128, (NB * S) / 128, 1), 256, 0, stream>>>(
      xb, 0, D, WobT, 0, D,
      (float*)d_out, 0, D, nullptr, 0, nullptr, 0, bo, D);
}

// Round 10
// 610.781 us; speedup vs baseline: 2.5493x; 1.0928x over previous
//
#include <hip/hip_runtime.h>
#include <hip/hip_bf16.h>

typedef __bf16 bf16_t;
typedef __bf16 bf16x8_t __attribute__((ext_vector_type(8)));
typedef __bf16 bf16x4_t __attribute__((ext_vector_type(4)));
typedef float f32x4_t __attribute__((ext_vector_type(4)));

#define EPI_RES_BF16 1
#define EPI_RELU_RES 2
#define EPI_BIAS 3

// async 16B global -> LDS (gfx950 global_load_lds_dwordx4)
__device__ __forceinline__ void gload_lds16(const bf16_t* g, bf16_t* l) {
  __builtin_amdgcn_global_load_lds(
      (const __attribute__((address_space(1))) void*)g,
      (__attribute__((address_space(3))) void*)l, 16, 0, 0);
}

__device__ __forceinline__ bf16x8_t ds_read_b128_bf16(unsigned addr) {
  bf16x8_t r;
  asm volatile("ds_read_b128 %0, %1" : "=v"(r) : "v"(addr));
  return r;
}

#define WAIT_VM(n) asm volatile("s_waitcnt vmcnt(" #n ")" ::: "memory")
#define WAIT_LGKM(n) asm volatile("s_waitcnt lgkmcnt(" #n ")" ::: "memory")
#define SCHED_FENCE __builtin_amdgcn_sched_barrier(0)

// ===========================================================================
// 256x256 8-phase bf16 GEMM (scores): C = alpha * A @ Bt^T, K multiple of 64,
// grid (N/256, M/256, batch), 512 threads = 8 waves (2M x 4N), BK=64.
// ROUND-5 BUILD VERBATIM (measured ~62us @ our shape, no spill).
// ===========================================================================
__global__ __launch_bounds__(512) void gemm256_bt_scale(
    const bf16_t* __restrict__ A, long aBatch, int lda,
    const bf16_t* __restrict__ Bt, long bBatch, int ldb,
    float* __restrict__ C, long cBatch, int ldc,
    float alpha, int K)
{
  extern __shared__ char smem[];
  typedef __attribute__((address_space(3))) char lds_char_t;
  const unsigned ldsBase = (unsigned)(size_t)(lds_char_t*)smem;

  const unsigned gx = gridDim.x, gy = gridDim.y;
  const unsigned nwg = gx * gy * gridDim.z;
  const unsigned lin = blockIdx.x + gx * (blockIdx.y + gy * blockIdx.z);
  const unsigned swz = (lin & 7u) * (nwg >> 3) + (lin >> 3);
  const unsigned bx = swz % gx;
  const unsigned tq = swz / gx;
  const unsigned by = tq % gy;
  const unsigned bz = tq / gy;

  A += (long)bz * aBatch;
  Bt += (long)bz * bBatch;
  C += (long)bz * cBatch;

  const int tid = threadIdx.x, wid = tid >> 6, lane = tid & 63;
  const int wm = wid >> 2, wn = wid & 3;     // 2M x 4N waves; per-wave out 128x64
  const int lr = lane & 15, lh = lane >> 4;
  const int sw2 = ((lr >> 3) & 1) << 1;
  const unsigned cbyte = (unsigned)((lh ^ sw2) << 4);

  const int gsw = ((lane >> 5) & 1) << 1;
  const int gcol = ((lane & 3) ^ gsw) << 3;
  const int grow = wid * 16 + (lane >> 2);
  const bf16_t* Ag = A + (long)(by * 256 + grow) * lda + gcol;
  const bf16_t* Bg = Bt + (long)(bx * 256 + grow) * ldb + gcol;

#define STAGE_A(KT, H, B_) do { \
    const bf16_t* _s = Ag + (long)(KT) * 64 + (H) * 32; \
    bf16_t* _d = (bf16_t*)(smem + (B_) * 32768 + (H) * 16384 + wid * 1024); \
    gload_lds16(_s, _d); \
    gload_lds16(_s + (long)128 * lda, (bf16_t*)((char*)_d + 8192)); \
  } while (0)
#define STAGE_B(KT, H, B_) do { \
    const bf16_t* _s = Bg + (long)(KT) * 64 + (H) * 32; \
    bf16_t* _d = (bf16_t*)(smem + 65536 + (B_) * 32768 + (H) * 16384 + wid * 1024); \
    gload_lds16(_s, _d); \
    gload_lds16(_s + (long)128 * ldb, (bf16_t*)((char*)_d + 8192)); \
  } while (0)

  const unsigned aAddr = ldsBase + (unsigned)((wm * 128 + lr) * 64) + cbyte;
  const unsigned bAddr = ldsBase + 65536u + (unsigned)((wn * 64 + lr) * 64) + cbyte;

  bf16x8_t aF[4], bF[4];
  f32x4_t acc[8][4] = {};

#define MFMA16(MH) do { \
    __builtin_amdgcn_s_setprio(1); \
    _Pragma("unroll") for (int _n = 0; _n < 4; ++_n) \
      _Pragma("unroll") for (int _m = 0; _m < 4; ++_m) \
        acc[(MH) * 4 + _m][_n] = __builtin_amdgcn_mfma_f32_16x16x32_bf16( \
            aF[_m], bF[_n], acc[(MH) * 4 + _m][_n], 0, 0, 0); \
    __builtin_amdgcn_s_setprio(0); \
  } while (0)

#define PHASE(MH, H, B_, STAGE_STMT, VM_STMT) do { \
    _Pragma("unroll") for (int _m = 0; _m < 4; ++_m) \
      aF[_m] = ds_read_b128_bf16(aAddr + (unsigned)(B_)*32768u + (H)*16384u + ((MH)*4 + _m)*1024u); \
    if ((MH) == 0) { \
      _Pragma("unroll") for (int _n = 0; _n < 4; ++_n) \
        bF[_n] = ds_read_b128_bf16(bAddr + (unsigned)(B_)*32768u + (H)*16384u + _n*1024u); \
    } \
    STAGE_STMT; \
    VM_STMT; \
    __builtin_amdgcn_s_barrier(); \
    WAIT_LGKM(0); \
    SCHED_FENCE; \
    MFMA16(MH); \
    __builtin_amdgcn_s_barrier(); \
    SCHED_FENCE; \
  } while (0)

  const int nt = K >> 6;  // >= 3

  STAGE_A(0, 0, 0); STAGE_B(0, 0, 0); STAGE_A(0, 1, 0); STAGE_B(0, 1, 0);
  STAGE_A(1, 0, 1); STAGE_B(1, 0, 1);
  WAIT_VM(8);
  __builtin_amdgcn_s_barrier();
  SCHED_FENCE;

  int bufc = 0;
  for (int kt = 0; kt < nt; ++kt, bufc ^= 1) {
    const int bo = bufc ^ 1;
    const bool st12 = (kt + 1 < nt);
    const bool st34 = (kt + 2 < nt);
    PHASE(0, 0, bufc, if (st12) STAGE_A(kt + 1, 1, bo), );
    PHASE(1, 0, bufc, if (st12) STAGE_B(kt + 1, 1, bo),
          if (kt == nt - 1) { WAIT_VM(0); } else { WAIT_VM(8); });
    PHASE(0, 1, bufc, if (st34) STAGE_A(kt + 2, 0, bufc), );
    PHASE(1, 1, bufc, if (st34) STAGE_B(kt + 2, 0, bufc),
          if (kt < nt - 2) { WAIT_VM(8); } else { WAIT_VM(4); });
  }

  const long r0 = (long)by * 256 + wm * 128;
  const int c0 = bx * 256 + wn * 64;
#pragma unroll
  for (int m = 0; m < 8; ++m)
#pragma unroll
    for (int n = 0; n < 4; ++n)
#pragma unroll
      for (int r = 0; r < 4; ++r)
        C[(r0 + m * 16 + lh * 4 + r) * ldc + c0 + n * 16 + lr] = acc[m][n][r] * alpha;

#undef PHASE
#undef MFMA16
#undef STAGE_A
#undef STAGE_B
}

// ===========================================================================
// 256x128 8-phase bf16 GEMM for PV / FFN / proj (ROUND-4/5 BUILD VERBATIM,
// measured PV ~63us, VGPR 60, no spill): C = epi(A @ Bt^T), BK=64.
// grid (N/128, M/256, batch) = 256 wgs. 512 threads = 8 waves (4M x 2N),
// per-wave 64x64. LDS 96 KiB dynamic; counted vmcnt(6).
// ===========================================================================
template <int EPI>
__global__ __launch_bounds__(512) void gemm256x128_bt(
    const bf16_t* __restrict__ A, long aBatch, int lda,
    const bf16_t* __restrict__ Bt, long bBatch, int ldb,
    float* __restrict__ Cf, long cfBatch, int ldc,
    bf16_t* __restrict__ Cb, long cbBatch,
    const float* __restrict__ Res, long resBatch,
    const float* __restrict__ bias, int K)
{
  extern __shared__ char smem[];
  typedef __attribute__((address_space(3))) char lds_char_t;
  const unsigned ldsBase = (unsigned)(size_t)(lds_char_t*)smem;

  const unsigned gx = gridDim.x, gy = gridDim.y;
  const unsigned nwg = gx * gy * gridDim.z;
  const unsigned lin = blockIdx.x + gx * (blockIdx.y + gy * blockIdx.z);
  const unsigned swz = (lin & 7u) * (nwg >> 3) + (lin >> 3);
  const unsigned bx = swz % gx;
  const unsigned tq = swz / gx;
  const unsigned by = tq % gy;
  const unsigned bz = tq / gy;

  A += (long)bz * aBatch;
  Bt += (long)bz * bBatch;
  Cf += (long)bz * cfBatch;
  if (Cb) Cb += (long)bz * cbBatch;
  if (Res) Res += (long)bz * resBatch;

  const int tid = threadIdx.x, wid = tid >> 6, lane = tid & 63;
  const int wm = wid >> 1, wn = wid & 1;     // 4M x 2N waves; per-wave out 64x64
  const int lr = lane & 15, lh = lane >> 4;
  const int sw2 = ((lr >> 3) & 1) << 1;
  const unsigned cbyte = (unsigned)((lh ^ sw2) << 4);

  const int gsw = ((lane >> 5) & 1) << 1;
  const int gcol = ((lane & 3) ^ gsw) << 3;
  const int grow = wid * 16 + (lane >> 2);
  const bf16_t* Ag = A + (long)(by * 256 + grow) * lda + gcol;
  const bf16_t* Bg = Bt + (long)(bx * 128 + grow) * ldb + gcol;

#define STAGE_A2(KT, H, B_) do { \
    const bf16_t* _s = Ag + (long)(KT) * 64 + (H) * 32; \
    bf16_t* _d = (bf16_t*)(smem + (B_) * 32768 + (H) * 16384 + wid * 1024); \
    gload_lds16(_s, _d); \
    gload_lds16(_s + (long)128 * lda, (bf16_t*)((char*)_d + 8192)); \
  } while (0)
#define STAGE_B1(KT, H, B_) do { \
    const bf16_t* _s = Bg + (long)(KT) * 64 + (H) * 32; \
    bf16_t* _d = (bf16_t*)(smem + 65536 + (B_) * 16384 + (H) * 8192 + wid * 1024); \
    gload_lds16(_s, _d); \
  } while (0)

  const unsigned aAddr = ldsBase + (unsigned)((wm * 64 + lr) * 64) + cbyte;
  const unsigned bAddr = ldsBase + 65536u + (unsigned)((wn * 64 + lr) * 64) + cbyte;

  bf16x8_t aF[4], bF[4];
  f32x4_t acc[4][4] = {};

#define PHASE(H, B_, STAGE_STMT, VM_STMT) do { \
    _Pragma("unroll") for (int _m = 0; _m < 4; ++_m) \
      aF[_m] = ds_read_b128_bf16(aAddr + (unsigned)(B_)*32768u + (H)*16384u + _m*1024u); \
    _Pragma("unroll") for (int _n = 0; _n < 4; ++_n) \
      bF[_n] = ds_read_b128_bf16(bAddr + (unsigned)(B_)*16384u + (H)*8192u + _n*1024u); \
    STAGE_STMT; \
    VM_STMT; \
    __builtin_amdgcn_s_barrier(); \
    WAIT_LGKM(0); \
    SCHED_FENCE; \
    __builtin_amdgcn_s_setprio(1); \
    _Pragma("unroll") for (int _n = 0; _n < 4; ++_n) \
      _Pragma("unroll") for (int _m = 0; _m < 4; ++_m) \
        acc[_m][_n] = __builtin_amdgcn_mfma_f32_16x16x32_bf16(aF[_m], bF[_n], acc[_m][_n], 0, 0, 0); \
    __builtin_amdgcn_s_setprio(0); \
    __builtin_amdgcn_s_barrier(); \
    SCHED_FENCE; \
  } while (0)

  const int nt = K >> 6;  // >= 3

  STAGE_A2(0, 0, 0); STAGE_B1(0, 0, 0);
  STAGE_A2(0, 1, 0); STAGE_B1(0, 1, 0);
  STAGE_A2(1, 0, 1); STAGE_B1(1, 0, 1);
  WAIT_VM(6);
  __builtin_amdgcn_s_barrier();
  SCHED_FENCE;

  int bufc = 0;
  for (int kt = 0; kt < nt; ++kt, bufc ^= 1) {
    const int bo = bufc ^ 1;
    PHASE(0, bufc,
          if (kt + 1 < nt) { STAGE_A2(kt + 1, 1, bo); STAGE_B1(kt + 1, 1, bo); },
          if (kt + 1 < nt) { WAIT_VM(6); } else { WAIT_VM(0); });
    PHASE(1, bufc,
          if (kt + 2 < nt) { STAGE_A2(kt + 2, 0, bufc); STAGE_B1(kt + 2, 0, bufc); },
          if (kt + 2 < nt) { WAIT_VM(6); } else if (kt + 1 < nt) { WAIT_VM(3); });
  }

  // epilogue: C/D layout col = lane&15, row = (lane>>4)*4 + reg
  const long r0 = (long)by * 256 + wm * 64;
  const int c0 = bx * 128 + wn * 64;
#pragma unroll
  for (int m = 0; m < 4; ++m) {
#pragma unroll
    for (int n = 0; n < 4; ++n) {
#pragma unroll
      for (int r = 0; r < 4; ++r) {
        const long row = r0 + m * 16 + lh * 4 + r;
        const int col = c0 + n * 16 + lr;
        const float v = acc[m][n][r];
        if constexpr (EPI == EPI_BIAS) {
          Cf[row * ldc + col] = v + bias[col];
        } else if constexpr (EPI == EPI_RES_BF16) {
          const float o = Res[row * ldc + col] + v;
          Cf[row * ldc + col] = o;
          Cb[row * ldc + col] = (bf16_t)o;
        } else {  // EPI_RELU_RES
          float t = v + bias[col];
          t = t > 0.f ? t : 0.f;
          const float o = Res[row * ldc + col] + t;
          Cf[row * ldc + col] = o;
          Cb[row * ldc + col] = (bf16_t)o;
        }
      }
    }
  }
#undef PHASE
#undef STAGE_A2
#undef STAGE_B1
}

// ---------------------------------------------------------------------------
// Row softmax over S f32 values; bf16 writeback to pout (compact stride S, or
// in-place at stride 2S as fallback). One block (256 thr) per row; the full
// f32 row is register-resident before any write, so both modes are race-free.
// ---------------------------------------------------------------------------
__global__ __launch_bounds__(256) void softmax_rows(
    const float* __restrict__ scores, bf16_t* __restrict__ pout,
    int S, long outStride)
{
  const long row = blockIdx.x;
  const float* p = scores + row * (long)S;
  bf16_t* out = pout + row * outStride;
  const int t = threadIdx.x;
  const int lane = t & 63, wave = t >> 6;

  float4 v0 = ((const float4*)p)[t * 2];
  float4 v1 = ((const float4*)p)[t * 2 + 1];
  float e[8] = {v0.x, v0.y, v0.z, v0.w, v1.x, v1.y, v1.z, v1.w};

  float m = e[0];
#pragma unroll
  for (int j = 1; j < 8; ++j) m = fmaxf(m, e[j]);
#pragma unroll
  for (int off = 32; off >= 1; off >>= 1) m = fmaxf(m, __shfl_xor(m, off));

  __shared__ float redm[4], reds[4];
  if (lane == 0) redm[wave] = m;
  __syncthreads();
  m = fmaxf(fmaxf(redm[0], redm[1]), fmaxf(redm[2], redm[3]));

  float s = 0.f;
#pragma unroll
  for (int j = 0; j < 8; ++j) { e[j] = __expf(e[j] - m); s += e[j]; }
#pragma unroll
  for (int off = 32; off >= 1; off >>= 1) s += __shfl_xor(s, off);
  if (lane == 0) reds[wave] = s;
  __syncthreads();
  s = reds[0] + reds[1] + reds[2] + reds[3];
  const float inv = 1.f / s;

  bf16x8_t ob;
#pragma unroll
  for (int j = 0; j < 8; ++j) ob[j] = (bf16_t)(e[j] * inv);
  ((bf16x8_t*)out)[t] = ob;
}

// ---------------------------------------------------------------------------
__global__ void cast_copy(const float* __restrict__ in, float* __restrict__ outf,
                          bf16_t* __restrict__ outb, long n4)
{
  long i = (long)blockIdx.x * blockDim.x + threadIdx.x;
  const long stride = (long)gridDim.x * blockDim.x;
  for (; i < n4; i += stride) {
    float4 v = ((const float4*)in)[i];
    ((float4*)outf)[i] = v;
    bf16x4_t bv;
    bv[0] = (bf16_t)v.x; bv[1] = (bf16_t)v.y; bv[2] = (bf16_t)v.z; bv[3] = (bf16_t)v.w;
    ((bf16x4_t*)outb)[i] = bv;
  }
}

// ---------------------------------------------------------------------------
__global__ void transpose_cast(const float* __restrict__ in, long inBatch, int R, int C,
                               bf16_t* __restrict__ out, long outBatch)
{
  __shared__ float tile[32][33];
  const float* src = in + (long)blockIdx.z * inBatch;
  bf16_t* dst = out + (long)blockIdx.z * outBatch;
  const int c0 = blockIdx.x * 32, r0 = blockIdx.y * 32;
  const int tx = threadIdx.x, ty = threadIdx.y;
#pragma unroll
  for (int i = 0; i < 32; i += 8) tile[ty + i][tx] = src[(long)(r0 + ty + i) * C + (c0 + tx)];
  __syncthreads();
#pragma unroll
  for (int i = 0; i < 32; i += 8)
    dst[(long)(c0 + ty + i) * R + (r0 + tx)] = (bf16_t)tile[tx][ty + i];
}

// ---------------------------------------------------------------------------
extern "C" void kernel_launch(void* const* d_in, const int* in_sizes, int n_in,
                              void* d_out, int out_size, void* d_ws, size_t ws_size,
                              hipStream_t stream)
{
  constexpr int L = 4, NB = 4, S = 2048, D = 1024;
  const float* x  = (const float*)d_in[0];
  const float* W  = (const float*)d_in[1];
  const float* bv = (const float*)d_in[2];
  const float* Wo = (const float*)d_in[3];
  const float* bo = (const float*)d_in[4];

  char* ws = (char*)d_ws;
  size_t off = 0;
  float* scores = (float*)(ws + off); off += (size_t)NB * S * S * 4;
  float* xf = (float*)(ws + off); off += (size_t)NB * S * D * 4;
  float* yf = (float*)(ws + off); off += (size_t)NB * S * D * 4;
  bf16_t* xb  = (bf16_t*)(ws + off); off += (size_t)NB * S * D * 2;
  bf16_t* xbT = (bf16_t*)(ws + off); off += (size_t)NB * S * D * 2;
  bf16_t* yb  = (bf16_t*)(ws + off); off += (size_t)NB * S * D * 2;
  bf16_t* WbT  = (bf16_t*)(ws + off); off += (size_t)L * D * D * 2;
  bf16_t* WobT = (bf16_t*)(ws + off); off += (size_t)D * D * 2;

  // Compact bf16 P buffer (stride S) if workspace permits; else fall back to
  // the in-place layout (bf16 rows at stride 2S inside the f32 scores buf).
  const size_t pbBytes = (size_t)NB * S * S * 2;
  bf16_t* Pb = nullptr;
  if (off + pbBytes <= ws_size) { Pb = (bf16_t*)(ws + off); off += pbBytes; }
  const bool compact = (Pb != nullptr);
  bf16_t* pOut = compact ? Pb : (bf16_t*)scores;
  const long pStride = compact ? (long)S : (long)2 * S;   // row stride (elems)
  const long pBatch  = compact ? (long)S * S : (long)2 * S * S;

  hipFuncSetAttribute((const void*)gemm256_bt_scale,
                      hipFuncAttributeMaxDynamicSharedMemorySize, 131072);
  hipFuncSetAttribute((const void*)gemm256x128_bt<EPI_RES_BF16>,
                      hipFuncAttributeMaxDynamicSharedMemorySize, 98304);
  hipFuncSetAttribute((const void*)gemm256x128_bt<EPI_RELU_RES>,
                      hipFuncAttributeMaxDynamicSharedMemorySize, 98304);
  hipFuncSetAttribute((const void*)gemm256x128_bt<EPI_BIAS>,
                      hipFuncAttributeMaxDynamicSharedMemorySize, 98304);

  const long n4 = (long)NB * S * D / 4;
  cast_copy<<<2048, 256, 0, stream>>>(x, xf, xb, n4);
  transpose_cast<<<dim3(D / 32, S / 32, NB), dim3(32, 8), 0, stream>>>(
      x, (long)S * D, S, D, xbT, (long)D * S);
  transpose_cast<<<dim3(D / 32, D / 32, L), dim3(32, 8), 0, stream>>>(
      W, (long)D * D, D, D, WbT, (long)D * D);
  transpose_cast<<<dim3(D / 32, D / 32, 1), dim3(32, 8), 0, stream>>>(
      Wo, 0, D, D, WobT, 0);

  const float inv_sqrt_d = 0.03125f;  // 1/sqrt(1024)

  for (int i = 0; i < L; ++i) {
    // scores = xb @ xb^T * inv_sqrt_d  (8-phase 256^2 kernel)
    gemm256_bt_scale<<<dim3(S / 256, S / 256, NB), 512, 131072, stream>>>(
        xb, (long)S * D, D, xb, (long)S * D, D,
        scores, (long)S * S, S, inv_sqrt_d, D);
    // softmax rows -> compact bf16 P (or in-place fallback)
    softmax_rows<<<NB * S, 256, 0, stream>>>(scores, pOut, S, pStride);
    // y = xf + P @ x   (Bt = xbT) — 256x128 8-phase
    gemm256x128_bt<EPI_RES_BF16><<<dim3(D / 128, S / 256, NB), 512, 98304, stream>>>(
        pOut, pBatch, (int)pStride, xbT, (long)D * S, S,
        yf, (long)S * D, D, yb, (long)S * D, xf, (long)S * D, nullptr, S);
    // z = yf + relu(yb @ W[i] + b[i])  -> xf, xb
    gemm256x128_bt<EPI_RELU_RES><<<dim3(D / 128, (NB * S) / 256, 1), 512, 98304, stream>>>(
        yb, 0, D, WbT + (size_t)i * D * D, 0, D,
        xf, 0, D, xb, 0, yf, 0, bv + (size_t)i * D, D);
    if (i < L - 1)
      transpose_cast<<<dim3(D / 32, S / 32, NB), dim3(32, 8), 0, stream>>>(
          xf, (long)S * D, S, D, xbT, (long)D * S);
  }

  // out = xb @ Wo + bo
  gemm256x128_bt<EPI_BIAS><<<dim3(D / 128, (NB * S) / 256, 1), 512, 98304, stream>>>(
      xb, 0, D, WobT, 0, D,
      (float*)d_out, 0, D, nullptr, 0, nullptr, 0, bo, D);
}

// Round 11
// 597.862 us; speedup vs baseline: 2.6044x; 1.0216x over previous
//
#include <hip/hip_runtime.h>
#include <hip/hip_bf16.h>

typedef __bf16 bf16_t;
typedef __bf16 bf16x8_t __attribute__((ext_vector_type(8)));
typedef __bf16 bf16x4_t __attribute__((ext_vector_type(4)));
typedef float f32x4_t __attribute__((ext_vector_type(4)));

#define EPI_RES_BF16 1
#define EPI_RELU_RES 2
#define EPI_BIAS 3

// async 16B global -> LDS (gfx950 global_load_lds_dwordx4)
__device__ __forceinline__ void gload_lds16(const bf16_t* g, bf16_t* l) {
  __builtin_amdgcn_global_load_lds(
      (const __attribute__((address_space(1))) void*)g,
      (__attribute__((address_space(3))) void*)l, 16, 0, 0);
}

__device__ __forceinline__ bf16x8_t ds_read_b128_bf16(unsigned addr) {
  bf16x8_t r;
  asm volatile("ds_read_b128 %0, %1" : "=v"(r) : "v"(addr));
  return r;
}

#define WAIT_VM(n) asm volatile("s_waitcnt vmcnt(" #n ")" ::: "memory")
#define WAIT_LGKM(n) asm volatile("s_waitcnt lgkmcnt(" #n ")" ::: "memory")
#define SCHED_FENCE __builtin_amdgcn_sched_barrier(0)

// ===========================================================================
// 256x256 one-barrier-per-phase bf16 GEMM (scores): C = alpha * A @ Bt^T.
// 512 thr = 8 waves (2M x 4N), per-wave 128x64. K chunks of 32, 4-slot ring
// per operand (16 KiB slots, 128 KiB total). Phase (chunk c, half mh):
//   ds_read frags -> [mh0: stage chunk c+2] / [mh1: vmcnt(4) retires c+1]
//   -> s_barrier -> lgkmcnt(0) -> 16 MFMA.   NO second barrier:
// stage targets the slot last read 2 phases back; every wave's reads of it
// were lgkm-drained before barrier(p-1), stage issues after barrier(p-1).
// ===========================================================================
__global__ __launch_bounds__(512) void gemm256_bt_scale(
    const bf16_t* __restrict__ A, long aBatch, int lda,
    const bf16_t* __restrict__ Bt, long bBatch, int ldb,
    float* __restrict__ C, long cBatch, int ldc,
    float alpha, int K)
{
  extern __shared__ char smem[];
  typedef __attribute__((address_space(3))) char lds_char_t;
  const unsigned ldsBase = (unsigned)(size_t)(lds_char_t*)smem;

  const unsigned gx = gridDim.x, gy = gridDim.y;
  const unsigned nwg = gx * gy * gridDim.z;
  const unsigned lin = blockIdx.x + gx * (blockIdx.y + gy * blockIdx.z);
  const unsigned swz = (lin & 7u) * (nwg >> 3) + (lin >> 3);
  const unsigned bx = swz % gx;
  const unsigned tq = swz / gx;
  const unsigned by = tq % gy;
  const unsigned bz = tq / gy;

  A += (long)bz * aBatch;
  Bt += (long)bz * bBatch;
  C += (long)bz * cBatch;

  const int tid = threadIdx.x, wid = tid >> 6, lane = tid & 63;
  const int wm = wid >> 2, wn = wid & 3;     // 2M x 4N waves; per-wave 128x64
  const int lr = lane & 15, lh = lane >> 4;
  const int sw2 = ((lr >> 3) & 1) << 1;
  const unsigned cbyte = (unsigned)((lh ^ sw2) << 4);

  const int gsw = ((lane >> 5) & 1) << 1;
  const int gcol = ((lane & 3) ^ gsw) << 3;
  const int grow = wid * 16 + (lane >> 2);
  const bf16_t* Ag = A + (long)(by * 256 + grow) * lda + gcol;
  const bf16_t* Bg = Bt + (long)(bx * 256 + grow) * ldb + gcol;

  // chunk c covers k = c*32..c*32+31 -> slot c&3 (A @ slot*16K, B @ 64K+slot*16K)
#define STAGE_CH(N_, SLOT) do { \
    const bf16_t* _sa = Ag + (long)(N_) * 32; \
    bf16_t* _da = (bf16_t*)(smem + (SLOT) * 16384 + wid * 1024); \
    gload_lds16(_sa, _da); \
    gload_lds16(_sa + (long)128 * lda, (bf16_t*)((char*)_da + 8192)); \
    const bf16_t* _sb = Bg + (long)(N_) * 32; \
    bf16_t* _db = (bf16_t*)(smem + 65536 + (SLOT) * 16384 + wid * 1024); \
    gload_lds16(_sb, _db); \
    gload_lds16(_sb + (long)128 * ldb, (bf16_t*)((char*)_db + 8192)); \
  } while (0)

  const unsigned aAddr = ldsBase + (unsigned)((wm * 128 + lr) * 64) + cbyte;
  const unsigned bAddr = ldsBase + 65536u + (unsigned)((wn * 64 + lr) * 64) + cbyte;

  bf16x8_t aF[4], bF[4];
  f32x4_t acc[8][4] = {};

#define MFMA16(MH) do { \
    __builtin_amdgcn_s_setprio(1); \
    _Pragma("unroll") for (int _n = 0; _n < 4; ++_n) \
      _Pragma("unroll") for (int _m = 0; _m < 4; ++_m) \
        acc[(MH) * 4 + _m][_n] = __builtin_amdgcn_mfma_f32_16x16x32_bf16( \
            aF[_m], bF[_n], acc[(MH) * 4 + _m][_n], 0, 0, 0); \
    __builtin_amdgcn_s_setprio(0); \
  } while (0)

  const int nc = K >> 5;  // chunks of 32; multiple of 4, >= 4

#define SPH(C_, MH, SLOT) do { \
    _Pragma("unroll") for (int _m = 0; _m < 4; ++_m) \
      aF[_m] = ds_read_b128_bf16(aAddr + (SLOT) * 16384u + ((MH) * 4 + _m) * 1024u); \
    if ((MH) == 0) { \
      _Pragma("unroll") for (int _n = 0; _n < 4; ++_n) \
        bF[_n] = ds_read_b128_bf16(bAddr + (SLOT) * 16384u + _n * 1024u); \
      if ((C_) + 2 < nc) STAGE_CH((C_) + 2, ((C_) + 2) & 3); \
    } else { \
      if ((C_) + 2 < nc) { WAIT_VM(4); } else { WAIT_VM(0); } \
    } \
    __builtin_amdgcn_s_barrier(); \
    WAIT_LGKM(0); \
    SCHED_FENCE; \
    MFMA16(MH); \
    SCHED_FENCE; \
  } while (0)

  // prologue: chunks 0,1 -> slots 0,1; retire chunk 0 (8 outstanding -> 4)
  STAGE_CH(0, 0); STAGE_CH(1, 1);
  WAIT_VM(4);
  __builtin_amdgcn_s_barrier();
  SCHED_FENCE;

  for (int c = 0; c < nc; c += 4) {
    SPH(c + 0, 0, 0); SPH(c + 0, 1, 0);
    SPH(c + 1, 0, 1); SPH(c + 1, 1, 1);
    SPH(c + 2, 0, 2); SPH(c + 2, 1, 2);
    SPH(c + 3, 0, 3); SPH(c + 3, 1, 3);
  }

  const long r0 = (long)by * 256 + wm * 128;
  const int c0 = bx * 256 + wn * 64;
#pragma unroll
  for (int m = 0; m < 8; ++m)
#pragma unroll
    for (int n = 0; n < 4; ++n)
#pragma unroll
      for (int r = 0; r < 4; ++r)
        C[(r0 + m * 16 + lh * 4 + r) * ldc + c0 + n * 16 + lr] = acc[m][n][r] * alpha;

#undef SPH
#undef MFMA16
#undef STAGE_CH
}

// ===========================================================================
// 256x128 one-barrier-per-phase bf16 GEMM (PV/FFN/proj): C = epi(A @ Bt^T).
// 512 thr = 8 waves (4M x 2N), per-wave 64x64. K chunks of 32, 4-slot ring
// (A 16 KiB, B 8 KiB slots; 96 KiB). Phase: 8 ds_read -> stage chunk c+2
// (3 gloads) -> vmcnt(3) retires c+1 -> barrier -> lgkm0 -> 16 MFMA.
// Same one-barrier proof as above (stage slot last read 2 phases back).
// ===========================================================================
template <int EPI>
__global__ __launch_bounds__(512) void gemm256x128_bt(
    const bf16_t* __restrict__ A, long aBatch, int lda,
    const bf16_t* __restrict__ Bt, long bBatch, int ldb,
    float* __restrict__ Cf, long cfBatch, int ldc,
    bf16_t* __restrict__ Cb, long cbBatch,
    const float* __restrict__ Res, long resBatch,
    const float* __restrict__ bias, int K)
{
  extern __shared__ char smem[];
  typedef __attribute__((address_space(3))) char lds_char_t;
  const unsigned ldsBase = (unsigned)(size_t)(lds_char_t*)smem;

  const unsigned gx = gridDim.x, gy = gridDim.y;
  const unsigned nwg = gx * gy * gridDim.z;
  const unsigned lin = blockIdx.x + gx * (blockIdx.y + gy * blockIdx.z);
  const unsigned swz = (lin & 7u) * (nwg >> 3) + (lin >> 3);
  const unsigned bx = swz % gx;
  const unsigned tq = swz / gx;
  const unsigned by = tq % gy;
  const unsigned bz = tq / gy;

  A += (long)bz * aBatch;
  Bt += (long)bz * bBatch;
  Cf += (long)bz * cfBatch;
  if (Cb) Cb += (long)bz * cbBatch;
  if (Res) Res += (long)bz * resBatch;

  const int tid = threadIdx.x, wid = tid >> 6, lane = tid & 63;
  const int wm = wid >> 1, wn = wid & 1;     // 4M x 2N waves; per-wave 64x64
  const int lr = lane & 15, lh = lane >> 4;
  const int sw2 = ((lr >> 3) & 1) << 1;
  const unsigned cbyte = (unsigned)((lh ^ sw2) << 4);

  const int gsw = ((lane >> 5) & 1) << 1;
  const int gcol = ((lane & 3) ^ gsw) << 3;
  const int grow = wid * 16 + (lane >> 2);
  const bf16_t* Ag = A + (long)(by * 256 + grow) * lda + gcol;
  const bf16_t* Bg = Bt + (long)(bx * 128 + grow) * ldb + gcol;

  // chunk c -> slot c&3: A @ slot*16K (256x32), B @ 64K + slot*8K (128x32)
#define STAGE_CH(N_, SLOT) do { \
    const bf16_t* _sa = Ag + (long)(N_) * 32; \
    bf16_t* _da = (bf16_t*)(smem + (SLOT) * 16384 + wid * 1024); \
    gload_lds16(_sa, _da); \
    gload_lds16(_sa + (long)128 * lda, (bf16_t*)((char*)_da + 8192)); \
    const bf16_t* _sb = Bg + (long)(N_) * 32; \
    bf16_t* _db = (bf16_t*)(smem + 65536 + (SLOT) * 8192 + wid * 1024); \
    gload_lds16(_sb, _db); \
  } while (0)

  const unsigned aAddr = ldsBase + (unsigned)((wm * 64 + lr) * 64) + cbyte;
  const unsigned bAddr = ldsBase + 65536u + (unsigned)((wn * 64 + lr) * 64) + cbyte;

  bf16x8_t aF[4], bF[4];
  f32x4_t acc[4][4] = {};

  const int nc = K >> 5;  // chunks of 32; multiple of 4, >= 4

#define PPH(C_, SLOT) do { \
    _Pragma("unroll") for (int _m = 0; _m < 4; ++_m) \
      aF[_m] = ds_read_b128_bf16(aAddr + (SLOT) * 16384u + _m * 1024u); \
    _Pragma("unroll") for (int _n = 0; _n < 4; ++_n) \
      bF[_n] = ds_read_b128_bf16(bAddr + (SLOT) * 8192u + _n * 1024u); \
    if ((C_) + 2 < nc) { STAGE_CH((C_) + 2, ((C_) + 2) & 3); WAIT_VM(3); } \
    else { WAIT_VM(0); } \
    __builtin_amdgcn_s_barrier(); \
    WAIT_LGKM(0); \
    SCHED_FENCE; \
    __builtin_amdgcn_s_setprio(1); \
    _Pragma("unroll") for (int _n = 0; _n < 4; ++_n) \
      _Pragma("unroll") for (int _m = 0; _m < 4; ++_m) \
        acc[_m][_n] = __builtin_amdgcn_mfma_f32_16x16x32_bf16(aF[_m], bF[_n], acc[_m][_n], 0, 0, 0); \
    __builtin_amdgcn_s_setprio(0); \
    SCHED_FENCE; \
  } while (0)

  // prologue: chunks 0,1 -> slots 0,1 (6 gloads); retire chunk 0 -> vmcnt(3)
  STAGE_CH(0, 0); STAGE_CH(1, 1);
  WAIT_VM(3);
  __builtin_amdgcn_s_barrier();
  SCHED_FENCE;

  for (int c = 0; c < nc; c += 4) {
    PPH(c + 0, 0);
    PPH(c + 1, 1);
    PPH(c + 2, 2);
    PPH(c + 3, 3);
  }

  // epilogue: C/D layout col = lane&15, row = (lane>>4)*4 + reg
  const long r0 = (long)by * 256 + wm * 64;
  const int c0 = bx * 128 + wn * 64;
#pragma unroll
  for (int m = 0; m < 4; ++m) {
#pragma unroll
    for (int n = 0; n < 4; ++n) {
#pragma unroll
      for (int r = 0; r < 4; ++r) {
        const long row = r0 + m * 16 + lh * 4 + r;
        const int col = c0 + n * 16 + lr;
        const float v = acc[m][n][r];
        if constexpr (EPI == EPI_BIAS) {
          Cf[row * ldc + col] = v + bias[col];
        } else if constexpr (EPI == EPI_RES_BF16) {
          const float o = Res[row * ldc + col] + v;
          Cf[row * ldc + col] = o;
          Cb[row * ldc + col] = (bf16_t)o;
        } else {  // EPI_RELU_RES
          float t = v + bias[col];
          t = t > 0.f ? t : 0.f;
          const float o = Res[row * ldc + col] + t;
          Cf[row * ldc + col] = o;
          Cb[row * ldc + col] = (bf16_t)o;
        }
      }
    }
  }
#undef PPH
#undef STAGE_CH
}

// ---------------------------------------------------------------------------
// Row softmax over S f32 values; bf16 writeback to pout (compact stride S).
// One block (256 thr) per row; full f32 row register-resident before writes.
// ---------------------------------------------------------------------------
__global__ __launch_bounds__(256) void softmax_rows(
    const float* __restrict__ scores, bf16_t* __restrict__ pout,
    int S, long outStride)
{
  const long row = blockIdx.x;
  const float* p = scores + row * (long)S;
  bf16_t* out = pout + row * outStride;
  const int t = threadIdx.x;
  const int lane = t & 63, wave = t >> 6;

  float4 v0 = ((const float4*)p)[t * 2];
  float4 v1 = ((const float4*)p)[t * 2 + 1];
  float e[8] = {v0.x, v0.y, v0.z, v0.w, v1.x, v1.y, v1.z, v1.w};

  float m = e[0];
#pragma unroll
  for (int j = 1; j < 8; ++j) m = fmaxf(m, e[j]);
#pragma unroll
  for (int off = 32; off >= 1; off >>= 1) m = fmaxf(m, __shfl_xor(m, off));

  __shared__ float redm[4], reds[4];
  if (lane == 0) redm[wave] = m;
  __syncthreads();
  m = fmaxf(fmaxf(redm[0], redm[1]), fmaxf(redm[2], redm[3]));

  float s = 0.f;
#pragma unroll
  for (int j = 0; j < 8; ++j) { e[j] = __expf(e[j] - m); s += e[j]; }
#pragma unroll
  for (int off = 32; off >= 1; off >>= 1) s += __shfl_xor(s, off);
  if (lane == 0) reds[wave] = s;
  __syncthreads();
  s = reds[0] + reds[1] + reds[2] + reds[3];
  const float inv = 1.f / s;

  bf16x8_t ob;
#pragma unroll
  for (int j = 0; j < 8; ++j) ob[j] = (bf16_t)(e[j] * inv);
  ((bf16x8_t*)out)[t] = ob;
}

// ---------------------------------------------------------------------------
__global__ void cast_copy(const float* __restrict__ in, float* __restrict__ outf,
                          bf16_t* __restrict__ outb, long n4)
{
  long i = (long)blockIdx.x * blockDim.x + threadIdx.x;
  const long stride = (long)gridDim.x * blockDim.x;
  for (; i < n4; i += stride) {
    float4 v = ((const float4*)in)[i];
    ((float4*)outf)[i] = v;
    bf16x4_t bv;
    bv[0] = (bf16_t)v.x; bv[1] = (bf16_t)v.y; bv[2] = (bf16_t)v.z; bv[3] = (bf16_t)v.w;
    ((bf16x4_t*)outb)[i] = bv;
  }
}

// ---------------------------------------------------------------------------
__global__ void transpose_cast(const float* __restrict__ in, long inBatch, int R, int C,
                               bf16_t* __restrict__ out, long outBatch)
{
  __shared__ float tile[32][33];
  const float* src = in + (long)blockIdx.z * inBatch;
  bf16_t* dst = out + (long)blockIdx.z * outBatch;
  const int c0 = blockIdx.x * 32, r0 = blockIdx.y * 32;
  const int tx = threadIdx.x, ty = threadIdx.y;
#pragma unroll
  for (int i = 0; i < 32; i += 8) tile[ty + i][tx] = src[(long)(r0 + ty + i) * C + (c0 + tx)];
  __syncthreads();
#pragma unroll
  for (int i = 0; i < 32; i += 8)
    dst[(long)(c0 + ty + i) * R + (r0 + tx)] = (bf16_t)tile[tx][ty + i];
}

// ---------------------------------------------------------------------------
extern "C" void kernel_launch(void* const* d_in, const int* in_sizes, int n_in,
                              void* d_out, int out_size, void* d_ws, size_t ws_size,
                              hipStream_t stream)
{
  constexpr int L = 4, NB = 4, S = 2048, D = 1024;
  const float* x  = (const float*)d_in[0];
  const float* W  = (const float*)d_in[1];
  const float* bv = (const float*)d_in[2];
  const float* Wo = (const float*)d_in[3];
  const float* bo = (const float*)d_in[4];

  char* ws = (char*)d_ws;
  size_t off = 0;
  float* scores = (float*)(ws + off); off += (size_t)NB * S * S * 4;
  float* xf = (float*)(ws + off); off += (size_t)NB * S * D * 4;
  float* yf = (float*)(ws + off); off += (size_t)NB * S * D * 4;
  bf16_t* xb  = (bf16_t*)(ws + off); off += (size_t)NB * S * D * 2;
  bf16_t* xbT = (bf16_t*)(ws + off); off += (size_t)NB * S * D * 2;
  bf16_t* yb  = (bf16_t*)(ws + off); off += (size_t)NB * S * D * 2;
  bf16_t* WbT  = (bf16_t*)(ws + off); off += (size_t)L * D * D * 2;
  bf16_t* WobT = (bf16_t*)(ws + off); off += (size_t)D * D * 2;

  // Compact bf16 P buffer (stride S) if workspace permits; else in-place.
  const size_t pbBytes = (size_t)NB * S * S * 2;
  bf16_t* Pb = nullptr;
  if (off + pbBytes <= ws_size) { Pb = (bf16_t*)(ws + off); off += pbBytes; }
  const bool compact = (Pb != nullptr);
  bf16_t* pOut = compact ? Pb : (bf16_t*)scores;
  const long pStride = compact ? (long)S : (long)2 * S;
  const long pBatch  = compact ? (long)S * S : (long)2 * S * S;

  hipFuncSetAttribute((const void*)gemm256_bt_scale,
                      hipFuncAttributeMaxDynamicSharedMemorySize, 131072);
  hipFuncSetAttribute((const void*)gemm256x128_bt<EPI_RES_BF16>,
                      hipFuncAttributeMaxDynamicSharedMemorySize, 98304);
  hipFuncSetAttribute((const void*)gemm256x128_bt<EPI_RELU_RES>,
                      hipFuncAttributeMaxDynamicSharedMemorySize, 98304);
  hipFuncSetAttribute((const void*)gemm256x128_bt<EPI_BIAS>,
                      hipFuncAttributeMaxDynamicSharedMemorySize, 98304);

  const long n4 = (long)NB * S * D / 4;
  cast_copy<<<2048, 256, 0, stream>>>(x, xf, xb, n4);
  transpose_cast<<<dim3(D / 32, S / 32, NB), dim3(32, 8), 0, stream>>>(
      x, (long)S * D, S, D, xbT, (long)D * S);
  transpose_cast<<<dim3(D / 32, D / 32, L), dim3(32, 8), 0, stream>>>(
      W, (long)D * D, D, D, WbT, (long)D * D);
  transpose_cast<<<dim3(D / 32, D / 32, 1), dim3(32, 8), 0, stream>>>(
      Wo, 0, D, D, WobT, 0);

  const float inv_sqrt_d = 0.03125f;  // 1/sqrt(1024)

  for (int i = 0; i < L; ++i) {
    // scores = xb @ xb^T * inv_sqrt_d
    gemm256_bt_scale<<<dim3(S / 256, S / 256, NB), 512, 131072, stream>>>(
        xb, (long)S * D, D, xb, (long)S * D, D,
        scores, (long)S * S, S, inv_sqrt_d, D);
    // softmax rows -> compact bf16 P
    softmax_rows<<<NB * S, 256, 0, stream>>>(scores, pOut, S, pStride);
    // y = xf + P @ x   (Bt = xbT)
    gemm256x128_bt<EPI_RES_BF16><<<dim3(D / 128, S / 256, NB), 512, 98304, stream>>>(
        pOut, pBatch, (int)pStride, xbT, (long)D * S, S,
        yf, (long)S * D, D, yb, (long)S * D, xf, (long)S * D, nullptr, S);
    // z = yf + relu(yb @ W[i] + b[i])  -> xf, xb
    gemm256x128_bt<EPI_RELU_RES><<<dim3(D / 128, (NB * S) / 256, 1), 512, 98304, stream>>>(
        yb, 0, D, WbT + (size_t)i * D * D, 0, D,
        xf, 0, D, xb, 0, yf, 0, bv + (size_t)i * D, D);
    if (i < L - 1)
      transpose_cast<<<dim3(D / 32, S / 32, NB), dim3(32, 8), 0, stream>>>(
          xf, (long)S * D, S, D, xbT, (long)D * S);
  }

  // out = xb @ Wo + bo
  gemm256x128_bt<EPI_BIAS><<<dim3(D / 128, (NB * S) / 256, 1), 512, 98304, stream>>>(
      xb, 0, D, WobT, 0, D,
      (float*)d_out, 0, D, nullptr, 0, nullptr, 0, bo, D);
}

// Round 12
// 596.204 us; speedup vs baseline: 2.6116x; 1.0028x over previous
//
#include <hip/hip_runtime.h>
#include <hip/hip_bf16.h>

typedef __bf16 bf16_t;
typedef __bf16 bf16x8_t __attribute__((ext_vector_type(8)));
typedef __bf16 bf16x4_t __attribute__((ext_vector_type(4)));
typedef float f32x4_t __attribute__((ext_vector_type(4)));

#define EPI_RES_BF16 1
#define EPI_RELU_RES 2
#define EPI_BIAS 3

// async 16B global -> LDS (gfx950 global_load_lds_dwordx4)
__device__ __forceinline__ void gload_lds16(const bf16_t* g, bf16_t* l) {
  __builtin_amdgcn_global_load_lds(
      (const __attribute__((address_space(1))) void*)g,
      (__attribute__((address_space(3))) void*)l, 16, 0, 0);
}

__device__ __forceinline__ bf16x8_t ds_read_b128_bf16(unsigned addr) {
  bf16x8_t r;
  asm volatile("ds_read_b128 %0, %1" : "=v"(r) : "v"(addr));
  return r;
}

#define WAIT_VM(n) asm volatile("s_waitcnt vmcnt(" #n ")" ::: "memory")
#define WAIT_LGKM(n) asm volatile("s_waitcnt lgkmcnt(" #n ")" ::: "memory")
#define SCHED_FENCE __builtin_amdgcn_sched_barrier(0)

// ===========================================================================
// 256x256 one-barrier-per-phase bf16 GEMM (scores): C = alpha * A @ Bt^T.
// ROUND-11 BUILD VERBATIM (passed, ~same as round-5 baseline).
// ===========================================================================
__global__ __launch_bounds__(512) void gemm256_bt_scale(
    const bf16_t* __restrict__ A, long aBatch, int lda,
    const bf16_t* __restrict__ Bt, long bBatch, int ldb,
    float* __restrict__ C, long cBatch, int ldc,
    float alpha, int K)
{
  extern __shared__ char smem[];
  typedef __attribute__((address_space(3))) char lds_char_t;
  const unsigned ldsBase = (unsigned)(size_t)(lds_char_t*)smem;

  const unsigned gx = gridDim.x, gy = gridDim.y;
  const unsigned nwg = gx * gy * gridDim.z;
  const unsigned lin = blockIdx.x + gx * (blockIdx.y + gy * blockIdx.z);
  const unsigned swz = (lin & 7u) * (nwg >> 3) + (lin >> 3);
  const unsigned bx = swz % gx;
  const unsigned tq = swz / gx;
  const unsigned by = tq % gy;
  const unsigned bz = tq / gy;

  A += (long)bz * aBatch;
  Bt += (long)bz * bBatch;
  C += (long)bz * cBatch;

  const int tid = threadIdx.x, wid = tid >> 6, lane = tid & 63;
  const int wm = wid >> 2, wn = wid & 3;     // 2M x 4N waves; per-wave 128x64
  const int lr = lane & 15, lh = lane >> 4;
  const int sw2 = ((lr >> 3) & 1) << 1;
  const unsigned cbyte = (unsigned)((lh ^ sw2) << 4);

  const int gsw = ((lane >> 5) & 1) << 1;
  const int gcol = ((lane & 3) ^ gsw) << 3;
  const int grow = wid * 16 + (lane >> 2);
  const bf16_t* Ag = A + (long)(by * 256 + grow) * lda + gcol;
  const bf16_t* Bg = Bt + (long)(bx * 256 + grow) * ldb + gcol;

#define STAGE_CH(N_, SLOT) do { \
    const bf16_t* _sa = Ag + (long)(N_) * 32; \
    bf16_t* _da = (bf16_t*)(smem + (SLOT) * 16384 + wid * 1024); \
    gload_lds16(_sa, _da); \
    gload_lds16(_sa + (long)128 * lda, (bf16_t*)((char*)_da + 8192)); \
    const bf16_t* _sb = Bg + (long)(N_) * 32; \
    bf16_t* _db = (bf16_t*)(smem + 65536 + (SLOT) * 16384 + wid * 1024); \
    gload_lds16(_sb, _db); \
    gload_lds16(_sb + (long)128 * ldb, (bf16_t*)((char*)_db + 8192)); \
  } while (0)

  const unsigned aAddr = ldsBase + (unsigned)((wm * 128 + lr) * 64) + cbyte;
  const unsigned bAddr = ldsBase + 65536u + (unsigned)((wn * 64 + lr) * 64) + cbyte;

  bf16x8_t aF[4], bF[4];
  f32x4_t acc[8][4] = {};

#define MFMA16(MH) do { \
    __builtin_amdgcn_s_setprio(1); \
    _Pragma("unroll") for (int _n = 0; _n < 4; ++_n) \
      _Pragma("unroll") for (int _m = 0; _m < 4; ++_m) \
        acc[(MH) * 4 + _m][_n] = __builtin_amdgcn_mfma_f32_16x16x32_bf16( \
            aF[_m], bF[_n], acc[(MH) * 4 + _m][_n], 0, 0, 0); \
    __builtin_amdgcn_s_setprio(0); \
  } while (0)

  const int nc = K >> 5;  // chunks of 32; multiple of 4, >= 4

#define SPH(C_, MH, SLOT) do { \
    _Pragma("unroll") for (int _m = 0; _m < 4; ++_m) \
      aF[_m] = ds_read_b128_bf16(aAddr + (SLOT) * 16384u + ((MH) * 4 + _m) * 1024u); \
    if ((MH) == 0) { \
      _Pragma("unroll") for (int _n = 0; _n < 4; ++_n) \
        bF[_n] = ds_read_b128_bf16(bAddr + (SLOT) * 16384u + _n * 1024u); \
      if ((C_) + 2 < nc) STAGE_CH((C_) + 2, ((C_) + 2) & 3); \
    } else { \
      if ((C_) + 2 < nc) { WAIT_VM(4); } else { WAIT_VM(0); } \
    } \
    __builtin_amdgcn_s_barrier(); \
    WAIT_LGKM(0); \
    SCHED_FENCE; \
    MFMA16(MH); \
    SCHED_FENCE; \
  } while (0)

  STAGE_CH(0, 0); STAGE_CH(1, 1);
  WAIT_VM(4);
  __builtin_amdgcn_s_barrier();
  SCHED_FENCE;

  for (int c = 0; c < nc; c += 4) {
    SPH(c + 0, 0, 0); SPH(c + 0, 1, 0);
    SPH(c + 1, 0, 1); SPH(c + 1, 1, 1);
    SPH(c + 2, 0, 2); SPH(c + 2, 1, 2);
    SPH(c + 3, 0, 3); SPH(c + 3, 1, 3);
  }

  const long r0 = (long)by * 256 + wm * 128;
  const int c0 = bx * 256 + wn * 64;
#pragma unroll
  for (int m = 0; m < 8; ++m)
#pragma unroll
    for (int n = 0; n < 4; ++n)
#pragma unroll
      for (int r = 0; r < 4; ++r)
        C[(r0 + m * 16 + lh * 4 + r) * ldc + c0 + n * 16 + lr] = acc[m][n][r] * alpha;

#undef SPH
#undef MFMA16
#undef STAGE_CH
}

// ===========================================================================
// 256x128 PIPELINED bf16 GEMM (PV/FFN/proj): C = epi(A @ Bt^T).
// 512 thr = 8 waves (4M x 2N), per-wave 64x64. K chunks of 32, 4-slot ring.
// Fragment registers DOUBLE-BUFFERED (aF/bF[2][4]) so reads(c+1) issue
// BEFORE MFMA(c); counted lgkmcnt(8) waits only reads(c) -> LDS service of
// reads(c+1) overlaps MFMA(c). Phase:
//   stage(c+2) -> vmcnt(3) [retires c+1] -> barrier
//   -> issue reads(c+1) into set[(c+1)&1] -> lgkmcnt(8) -> 16 MFMA on set[c&1]
// Safety: stage target slot was lgkm-drained 2 phases (>=2 barriers) earlier;
// reads(c+1) only after barrier that follows every wave's vm-retire of c+1;
// last phase uses lgkmcnt(0) (counted-8 would pass trivially with no new reads).
// ===========================================================================
template <int EPI>
__global__ __launch_bounds__(512) void gemm256x128_bt(
    const bf16_t* __restrict__ A, long aBatch, int lda,
    const bf16_t* __restrict__ Bt, long bBatch, int ldb,
    float* __restrict__ Cf, long cfBatch, int ldc,
    bf16_t* __restrict__ Cb, long cbBatch,
    const float* __restrict__ Res, long resBatch,
    const float* __restrict__ bias, int K)
{
  extern __shared__ char smem[];
  typedef __attribute__((address_space(3))) char lds_char_t;
  const unsigned ldsBase = (unsigned)(size_t)(lds_char_t*)smem;

  const unsigned gx = gridDim.x, gy = gridDim.y;
  const unsigned nwg = gx * gy * gridDim.z;
  const unsigned lin = blockIdx.x + gx * (blockIdx.y + gy * blockIdx.z);
  const unsigned swz = (lin & 7u) * (nwg >> 3) + (lin >> 3);
  const unsigned bx = swz % gx;
  const unsigned tq = swz / gx;
  const unsigned by = tq % gy;
  const unsigned bz = tq / gy;

  A += (long)bz * aBatch;
  Bt += (long)bz * bBatch;
  Cf += (long)bz * cfBatch;
  if (Cb) Cb += (long)bz * cbBatch;
  if (Res) Res += (long)bz * resBatch;

  const int tid = threadIdx.x, wid = tid >> 6, lane = tid & 63;
  const int wm = wid >> 1, wn = wid & 1;     // 4M x 2N waves; per-wave 64x64
  const int lr = lane & 15, lh = lane >> 4;
  const int sw2 = ((lr >> 3) & 1) << 1;
  const unsigned cbyte = (unsigned)((lh ^ sw2) << 4);

  const int gsw = ((lane >> 5) & 1) << 1;
  const int gcol = ((lane & 3) ^ gsw) << 3;
  const int grow = wid * 16 + (lane >> 2);
  const bf16_t* Ag = A + (long)(by * 256 + grow) * lda + gcol;
  const bf16_t* Bg = Bt + (long)(bx * 128 + grow) * ldb + gcol;

  // chunk c -> slot c&3: A @ slot*16K (256x32), B @ 64K + slot*8K (128x32)
#define STAGE_CH(N_, SLOT) do { \
    const bf16_t* _sa = Ag + (long)(N_) * 32; \
    bf16_t* _da = (bf16_t*)(smem + (SLOT) * 16384 + wid * 1024); \
    gload_lds16(_sa, _da); \
    gload_lds16(_sa + (long)128 * lda, (bf16_t*)((char*)_da + 8192)); \
    const bf16_t* _sb = Bg + (long)(N_) * 32; \
    bf16_t* _db = (bf16_t*)(smem + 65536 + (SLOT) * 8192 + wid * 1024); \
    gload_lds16(_sb, _db); \
  } while (0)

  const unsigned aAddr = ldsBase + (unsigned)((wm * 64 + lr) * 64) + cbyte;
  const unsigned bAddr = ldsBase + 65536u + (unsigned)((wn * 64 + lr) * 64) + cbyte;

  bf16x8_t aF[2][4], bF[2][4];   // double-buffered fragment sets
  f32x4_t acc[4][4] = {};

  const int nc = K >> 5;  // chunks of 32; multiple of 4, >= 4

#define RD_CHUNK(SET, SLOT) do { \
    _Pragma("unroll") for (int _m = 0; _m < 4; ++_m) \
      aF[SET][_m] = ds_read_b128_bf16(aAddr + (SLOT) * 16384u + _m * 1024u); \
    _Pragma("unroll") for (int _n = 0; _n < 4; ++_n) \
      bF[SET][_n] = ds_read_b128_bf16(bAddr + (SLOT) * 8192u + _n * 1024u); \
  } while (0)

#define PPH(C_, SLOT, CUR, NXT) do { \
    if ((C_) + 2 < nc) { STAGE_CH((C_) + 2, ((C_) + 2) & 3); WAIT_VM(3); } \
    else { WAIT_VM(0); } \
    __builtin_amdgcn_s_barrier(); \
    if ((C_) + 1 < nc) { \
      RD_CHUNK(NXT, ((SLOT) + 1) & 3); \
      WAIT_LGKM(8); \
    } else { \
      WAIT_LGKM(0); \
    } \
    SCHED_FENCE; \
    __builtin_amdgcn_s_setprio(1); \
    _Pragma("unroll") for (int _n = 0; _n < 4; ++_n) \
      _Pragma("unroll") for (int _m = 0; _m < 4; ++_m) \
        acc[_m][_n] = __builtin_amdgcn_mfma_f32_16x16x32_bf16( \
            aF[CUR][_m], bF[CUR][_n], acc[_m][_n], 0, 0, 0); \
    __builtin_amdgcn_s_setprio(0); \
    SCHED_FENCE; \
  } while (0)

  // prologue: chunks 0,1 staged; retire chunk 0; reads(0) -> set 0
  STAGE_CH(0, 0); STAGE_CH(1, 1);
  WAIT_VM(3);
  __builtin_amdgcn_s_barrier();
  RD_CHUNK(0, 0);
  SCHED_FENCE;

  for (int c = 0; c < nc; c += 4) {
    PPH(c + 0, 0, 0, 1);
    PPH(c + 1, 1, 1, 0);
    PPH(c + 2, 2, 0, 1);
    PPH(c + 3, 3, 1, 0);
  }

  // epilogue: C/D layout col = lane&15, row = (lane>>4)*4 + reg
  const long r0 = (long)by * 256 + wm * 64;
  const int c0 = bx * 128 + wn * 64;
#pragma unroll
  for (int m = 0; m < 4; ++m) {
#pragma unroll
    for (int n = 0; n < 4; ++n) {
#pragma unroll
      for (int r = 0; r < 4; ++r) {
        const long row = r0 + m * 16 + lh * 4 + r;
        const int col = c0 + n * 16 + lr;
        const float v = acc[m][n][r];
        if constexpr (EPI == EPI_BIAS) {
          Cf[row * ldc + col] = v + bias[col];
        } else if constexpr (EPI == EPI_RES_BF16) {
          const float o = Res[row * ldc + col] + v;
          Cf[row * ldc + col] = o;
          Cb[row * ldc + col] = (bf16_t)o;
        } else {  // EPI_RELU_RES
          float t = v + bias[col];
          t = t > 0.f ? t : 0.f;
          const float o = Res[row * ldc + col] + t;
          Cf[row * ldc + col] = o;
          Cb[row * ldc + col] = (bf16_t)o;
        }
      }
    }
  }
#undef PPH
#undef RD_CHUNK
#undef STAGE_CH
}

// ---------------------------------------------------------------------------
// Row softmax over S f32 values; bf16 writeback to pout (compact stride S).
// ---------------------------------------------------------------------------
__global__ __launch_bounds__(256) void softmax_rows(
    const float* __restrict__ scores, bf16_t* __restrict__ pout,
    int S, long outStride)
{
  const long row = blockIdx.x;
  const float* p = scores + row * (long)S;
  bf16_t* out = pout + row * outStride;
  const int t = threadIdx.x;
  const int lane = t & 63, wave = t >> 6;

  float4 v0 = ((const float4*)p)[t * 2];
  float4 v1 = ((const float4*)p)[t * 2 + 1];
  float e[8] = {v0.x, v0.y, v0.z, v0.w, v1.x, v1.y, v1.z, v1.w};

  float m = e[0];
#pragma unroll
  for (int j = 1; j < 8; ++j) m = fmaxf(m, e[j]);
#pragma unroll
  for (int off = 32; off >= 1; off >>= 1) m = fmaxf(m, __shfl_xor(m, off));

  __shared__ float redm[4], reds[4];
  if (lane == 0) redm[wave] = m;
  __syncthreads();
  m = fmaxf(fmaxf(redm[0], redm[1]), fmaxf(redm[2], redm[3]));

  float s = 0.f;
#pragma unroll
  for (int j = 0; j < 8; ++j) { e[j] = __expf(e[j] - m); s += e[j]; }
#pragma unroll
  for (int off = 32; off >= 1; off >>= 1) s += __shfl_xor(s, off);
  if (lane == 0) reds[wave] = s;
  __syncthreads();
  s = reds[0] + reds[1] + reds[2] + reds[3];
  const float inv = 1.f / s;

  bf16x8_t ob;
#pragma unroll
  for (int j = 0; j < 8; ++j) ob[j] = (bf16_t)(e[j] * inv);
  ((bf16x8_t*)out)[t] = ob;
}

// ---------------------------------------------------------------------------
__global__ void cast_copy(const float* __restrict__ in, float* __restrict__ outf,
                          bf16_t* __restrict__ outb, long n4)
{
  long i = (long)blockIdx.x * blockDim.x + threadIdx.x;
  const long stride = (long)gridDim.x * blockDim.x;
  for (; i < n4; i += stride) {
    float4 v = ((const float4*)in)[i];
    ((float4*)outf)[i] = v;
    bf16x4_t bv;
    bv[0] = (bf16_t)v.x; bv[1] = (bf16_t)v.y; bv[2] = (bf16_t)v.z; bv[3] = (bf16_t)v.w;
    ((bf16x4_t*)outb)[i] = bv;
  }
}

// ---------------------------------------------------------------------------
__global__ void transpose_cast(const float* __restrict__ in, long inBatch, int R, int C,
                               bf16_t* __restrict__ out, long outBatch)
{
  __shared__ float tile[32][33];
  const float* src = in + (long)blockIdx.z * inBatch;
  bf16_t* dst = out + (long)blockIdx.z * outBatch;
  const int c0 = blockIdx.x * 32, r0 = blockIdx.y * 32;
  const int tx = threadIdx.x, ty = threadIdx.y;
#pragma unroll
  for (int i = 0; i < 32; i += 8) tile[ty + i][tx] = src[(long)(r0 + ty + i) * C + (c0 + tx)];
  __syncthreads();
#pragma unroll
  for (int i = 0; i < 32; i += 8)
    dst[(long)(c0 + ty + i) * R + (r0 + tx)] = (bf16_t)tile[tx][ty + i];
}

// ---------------------------------------------------------------------------
extern "C" void kernel_launch(void* const* d_in, const int* in_sizes, int n_in,
                              void* d_out, int out_size, void* d_ws, size_t ws_size,
                              hipStream_t stream)
{
  constexpr int L = 4, NB = 4, S = 2048, D = 1024;
  const float* x  = (const float*)d_in[0];
  const float* W  = (const float*)d_in[1];
  const float* bv = (const float*)d_in[2];
  const float* Wo = (const float*)d_in[3];
  const float* bo = (const float*)d_in[4];

  char* ws = (char*)d_ws;
  size_t off = 0;
  float* scores = (float*)(ws + off); off += (size_t)NB * S * S * 4;
  float* xf = (float*)(ws + off); off += (size_t)NB * S * D * 4;
  float* yf = (float*)(ws + off); off += (size_t)NB * S * D * 4;
  bf16_t* xb  = (bf16_t*)(ws + off); off += (size_t)NB * S * D * 2;
  bf16_t* xbT = (bf16_t*)(ws + off); off += (size_t)NB * S * D * 2;
  bf16_t* yb  = (bf16_t*)(ws + off); off += (size_t)NB * S * D * 2;
  bf16_t* WbT  = (bf16_t*)(ws + off); off += (size_t)L * D * D * 2;
  bf16_t* WobT = (bf16_t*)(ws + off); off += (size_t)D * D * 2;

  // Compact bf16 P buffer (stride S) if workspace permits; else in-place.
  const size_t pbBytes = (size_t)NB * S * S * 2;
  bf16_t* Pb = nullptr;
  if (off + pbBytes <= ws_size) { Pb = (bf16_t*)(ws + off); off += pbBytes; }
  const bool compact = (Pb != nullptr);
  bf16_t* pOut = compact ? Pb : (bf16_t*)scores;
  const long pStride = compact ? (long)S : (long)2 * S;
  const long pBatch  = compact ? (long)S * S : (long)2 * S * S;

  hipFuncSetAttribute((const void*)gemm256_bt_scale,
                      hipFuncAttributeMaxDynamicSharedMemorySize, 131072);
  hipFuncSetAttribute((const void*)gemm256x128_bt<EPI_RES_BF16>,
                      hipFuncAttributeMaxDynamicSharedMemorySize, 98304);
  hipFuncSetAttribute((const void*)gemm256x128_bt<EPI_RELU_RES>,
                      hipFuncAttributeMaxDynamicSharedMemorySize, 98304);
  hipFuncSetAttribute((const void*)gemm256x128_bt<EPI_BIAS>,
                      hipFuncAttributeMaxDynamicSharedMemorySize, 98304);

  const long n4 = (long)NB * S * D / 4;
  cast_copy<<<2048, 256, 0, stream>>>(x, xf, xb, n4);
  transpose_cast<<<dim3(D / 32, S / 32, NB), dim3(32, 8), 0, stream>>>(
      x, (long)S * D, S, D, xbT, (long)D * S);
  transpose_cast<<<dim3(D / 32, D / 32, L), dim3(32, 8), 0, stream>>>(
      W, (long)D * D, D, D, WbT, (long)D * D);
  transpose_cast<<<dim3(D / 32, D / 32, 1), dim3(32, 8), 0, stream>>>(
      Wo, 0, D, D, WobT, 0);

  const float inv_sqrt_d = 0.03125f;  // 1/sqrt(1024)

  for (int i = 0; i < L; ++i) {
    // scores = xb @ xb^T * inv_sqrt_d
    gemm256_bt_scale<<<dim3(S / 256, S / 256, NB), 512, 131072, stream>>>(
        xb, (long)S * D, D, xb, (long)S * D, D,
        scores, (long)S * S, S, inv_sqrt_d, D);
    // softmax rows -> compact bf16 P
    softmax_rows<<<NB * S, 256, 0, stream>>>(scores, pOut, S, pStride);
    // y = xf + P @ x   (Bt = xbT)
    gemm256x128_bt<EPI_RES_BF16><<<dim3(D / 128, S / 256, NB), 512, 98304, stream>>>(
        pOut, pBatch, (int)pStride, xbT, (long)D * S, S,
        yf, (long)S * D, D, yb, (long)S * D, xf, (long)S * D, nullptr, S);
    // z = yf + relu(yb @ W[i] + b[i])  -> xf, xb
    gemm256x128_bt<EPI_RELU_RES><<<dim3(D / 128, (NB * S) / 256, 1), 512, 98304, stream>>>(
        yb, 0, D, WbT + (size_t)i * D * D, 0, D,
        xf, 0, D, xb, 0, yf, 0, bv + (size_t)i * D, D);
    if (i < L - 1)
      transpose_cast<<<dim3(D / 32, S / 32, NB), dim3(32, 8), 0, stream>>>(
          xf, (long)S * D, S, D, xbT, (long)D * S);
  }

  // out = xb @ Wo + bo
  gemm256x128_bt<EPI_BIAS><<<dim3(D / 128, (NB * S) / 256, 1), 512, 98304, stream>>>(
      xb, 0, D, WobT, 0, D,
      (float*)d_out, 0, D, nullptr, 0, nullptr, 0, bo, D);
}

// Round 13
// 591.985 us; speedup vs baseline: 2.6302x; 1.0071x over previous
//
#include <hip/hip_runtime.h>
#include <hip/hip_bf16.h>

typedef __bf16 bf16_t;
typedef __bf16 bf16x8_t __attribute__((ext_vector_type(8)));
typedef __bf16 bf16x4_t __attribute__((ext_vector_type(4)));
typedef float f32x4_t __attribute__((ext_vector_type(4)));

#define EPI_RES_BF16 1
#define EPI_RELU_RES 2
#define EPI_BIAS 3

// async 16B global -> LDS (gfx950 global_load_lds_dwordx4)
__device__ __forceinline__ void gload_lds16(const bf16_t* g, bf16_t* l) {
  __builtin_amdgcn_global_load_lds(
      (const __attribute__((address_space(1))) void*)g,
      (__attribute__((address_space(3))) void*)l, 16, 0, 0);
}

__device__ __forceinline__ bf16x8_t ds_read_b128_bf16(unsigned addr) {
  bf16x8_t r;
  asm volatile("ds_read_b128 %0, %1" : "=v"(r) : "v"(addr));
  return r;
}

#define WAIT_VM(n) asm volatile("s_waitcnt vmcnt(" #n ")" ::: "memory")
#define WAIT_LGKM(n) asm volatile("s_waitcnt lgkmcnt(" #n ")" ::: "memory")
#define SCHED_FENCE __builtin_amdgcn_sched_barrier(0)

// ===========================================================================
// 256x256 one-barrier-per-phase bf16 GEMM (scores): C = alpha * A @ Bt^T.
// ROUND-11/12 BUILD VERBATIM (passed).
// ===========================================================================
__global__ __launch_bounds__(512) void gemm256_bt_scale(
    const bf16_t* __restrict__ A, long aBatch, int lda,
    const bf16_t* __restrict__ Bt, long bBatch, int ldb,
    float* __restrict__ C, long cBatch, int ldc,
    float alpha, int K)
{
  extern __shared__ char smem[];
  typedef __attribute__((address_space(3))) char lds_char_t;
  const unsigned ldsBase = (unsigned)(size_t)(lds_char_t*)smem;

  const unsigned gx = gridDim.x, gy = gridDim.y;
  const unsigned nwg = gx * gy * gridDim.z;
  const unsigned lin = blockIdx.x + gx * (blockIdx.y + gy * blockIdx.z);
  const unsigned swz = (lin & 7u) * (nwg >> 3) + (lin >> 3);
  const unsigned bx = swz % gx;
  const unsigned tq = swz / gx;
  const unsigned by = tq % gy;
  const unsigned bz = tq / gy;

  A += (long)bz * aBatch;
  Bt += (long)bz * bBatch;
  C += (long)bz * cBatch;

  const int tid = threadIdx.x, wid = tid >> 6, lane = tid & 63;
  const int wm = wid >> 2, wn = wid & 3;     // 2M x 4N waves; per-wave 128x64
  const int lr = lane & 15, lh = lane >> 4;
  const int sw2 = ((lr >> 3) & 1) << 1;
  const unsigned cbyte = (unsigned)((lh ^ sw2) << 4);

  const int gsw = ((lane >> 5) & 1) << 1;
  const int gcol = ((lane & 3) ^ gsw) << 3;
  const int grow = wid * 16 + (lane >> 2);
  const bf16_t* Ag = A + (long)(by * 256 + grow) * lda + gcol;
  const bf16_t* Bg = Bt + (long)(bx * 256 + grow) * ldb + gcol;

#define STAGE_CH(N_, SLOT) do { \
    const bf16_t* _sa = Ag + (long)(N_) * 32; \
    bf16_t* _da = (bf16_t*)(smem + (SLOT) * 16384 + wid * 1024); \
    gload_lds16(_sa, _da); \
    gload_lds16(_sa + (long)128 * lda, (bf16_t*)((char*)_da + 8192)); \
    const bf16_t* _sb = Bg + (long)(N_) * 32; \
    bf16_t* _db = (bf16_t*)(smem + 65536 + (SLOT) * 16384 + wid * 1024); \
    gload_lds16(_sb, _db); \
    gload_lds16(_sb + (long)128 * ldb, (bf16_t*)((char*)_db + 8192)); \
  } while (0)

  const unsigned aAddr = ldsBase + (unsigned)((wm * 128 + lr) * 64) + cbyte;
  const unsigned bAddr = ldsBase + 65536u + (unsigned)((wn * 64 + lr) * 64) + cbyte;

  bf16x8_t aF[4], bF[4];
  f32x4_t acc[8][4] = {};

#define MFMA16(MH) do { \
    __builtin_amdgcn_s_setprio(1); \
    _Pragma("unroll") for (int _n = 0; _n < 4; ++_n) \
      _Pragma("unroll") for (int _m = 0; _m < 4; ++_m) \
        acc[(MH) * 4 + _m][_n] = __builtin_amdgcn_mfma_f32_16x16x32_bf16( \
            aF[_m], bF[_n], acc[(MH) * 4 + _m][_n], 0, 0, 0); \
    __builtin_amdgcn_s_setprio(0); \
  } while (0)

  const int nc = K >> 5;  // chunks of 32; multiple of 4, >= 4

#define SPH(C_, MH, SLOT) do { \
    _Pragma("unroll") for (int _m = 0; _m < 4; ++_m) \
      aF[_m] = ds_read_b128_bf16(aAddr + (SLOT) * 16384u + ((MH) * 4 + _m) * 1024u); \
    if ((MH) == 0) { \
      _Pragma("unroll") for (int _n = 0; _n < 4; ++_n) \
        bF[_n] = ds_read_b128_bf16(bAddr + (SLOT) * 16384u + _n * 1024u); \
      if ((C_) + 2 < nc) STAGE_CH((C_) + 2, ((C_) + 2) & 3); \
    } else { \
      if ((C_) + 2 < nc) { WAIT_VM(4); } else { WAIT_VM(0); } \
    } \
    __builtin_amdgcn_s_barrier(); \
    WAIT_LGKM(0); \
    SCHED_FENCE; \
    MFMA16(MH); \
    SCHED_FENCE; \
  } while (0)

  STAGE_CH(0, 0); STAGE_CH(1, 1);
  WAIT_VM(4);
  __builtin_amdgcn_s_barrier();
  SCHED_FENCE;

  for (int c = 0; c < nc; c += 4) {
    SPH(c + 0, 0, 0); SPH(c + 0, 1, 0);
    SPH(c + 1, 0, 1); SPH(c + 1, 1, 1);
    SPH(c + 2, 0, 2); SPH(c + 2, 1, 2);
    SPH(c + 3, 0, 3); SPH(c + 3, 1, 3);
  }

  const long r0 = (long)by * 256 + wm * 128;
  const int c0 = bx * 256 + wn * 64;
#pragma unroll
  for (int m = 0; m < 8; ++m)
#pragma unroll
    for (int n = 0; n < 4; ++n)
#pragma unroll
      for (int r = 0; r < 4; ++r)
        C[(r0 + m * 16 + lh * 4 + r) * ldc + c0 + n * 16 + lr] = acc[m][n][r] * alpha;

#undef SPH
#undef MFMA16
#undef STAGE_CH
}

// ===========================================================================
// 128x128 one-barrier-per-phase bf16 GEMM (PV/FFN/proj), 2 wg/CU:
// 256 thr = 4 waves (2M x 2N), per-wave 64x64. K chunks of 32, 4-slot ring
// (A 8 KiB + B 8 KiB per slot = 64 KiB LDS total -> 2 independent wgs/CU so
// one wg's MFMA overlaps the other's LDS/barrier stalls — m114 overlap).
// Phase: 8 ds_read(c) -> stage(c+2, 4 gloads) -> vmcnt(4) [retires c+1]
//        -> barrier -> lgkm0 -> 16 MFMA.  (round-11 phase code, 4-wave geometry)
// ===========================================================================
template <int EPI>
__global__ __launch_bounds__(256) void gemm128_bt(
    const bf16_t* __restrict__ A, long aBatch, int lda,
    const bf16_t* __restrict__ Bt, long bBatch, int ldb,
    float* __restrict__ Cf, long cfBatch, int ldc,
    bf16_t* __restrict__ Cb, long cbBatch,
    const float* __restrict__ Res, long resBatch,
    const float* __restrict__ bias, int K)
{
  extern __shared__ char smem[];
  typedef __attribute__((address_space(3))) char lds_char_t;
  const unsigned ldsBase = (unsigned)(size_t)(lds_char_t*)smem;

  const unsigned gx = gridDim.x, gy = gridDim.y;
  const unsigned nwg = gx * gy * gridDim.z;
  const unsigned lin = blockIdx.x + gx * (blockIdx.y + gy * blockIdx.z);
  const unsigned swz = (lin & 7u) * (nwg >> 3) + (lin >> 3);
  const unsigned bx = swz % gx;
  const unsigned tq = swz / gx;
  const unsigned by = tq % gy;
  const unsigned bz = tq / gy;

  A += (long)bz * aBatch;
  Bt += (long)bz * bBatch;
  Cf += (long)bz * cfBatch;
  if (Cb) Cb += (long)bz * cbBatch;
  if (Res) Res += (long)bz * resBatch;

  const int tid = threadIdx.x, wid = tid >> 6, lane = tid & 63;
  const int wm = wid >> 1, wn = wid & 1;     // 2M x 2N waves; per-wave 64x64
  const int lr = lane & 15, lh = lane >> 4;
  const int sw2 = ((lr >> 3) & 1) << 1;
  const unsigned cbyte = (unsigned)((lh ^ sw2) << 4);

  // staging: wave w covers rows w*16 + lane/4 (+64 for 2nd issue); source col
  // pre-swizzled by row bit3 (= lane bit5); LDS dest linear (rule 21)
  const int gsw = ((lane >> 5) & 1) << 1;
  const int gcol = ((lane & 3) ^ gsw) << 3;
  const int grow = wid * 16 + (lane >> 2);
  const bf16_t* Ag = A + (long)(by * 128 + grow) * lda + gcol;
  const bf16_t* Bg = Bt + (long)(bx * 128 + grow) * ldb + gcol;

  // chunk c -> slot c&3: A 8K @ slot*16K, B 8K @ slot*16K + 8K
#define STAGE_CH(N_, SLOT) do { \
    const bf16_t* _sa = Ag + (long)(N_) * 32; \
    bf16_t* _da = (bf16_t*)(smem + (SLOT) * 16384 + wid * 1024); \
    gload_lds16(_sa, _da); \
    gload_lds16(_sa + (long)64 * lda, (bf16_t*)((char*)_da + 4096)); \
    const bf16_t* _sb = Bg + (long)(N_) * 32; \
    bf16_t* _db = (bf16_t*)(smem + (SLOT) * 16384 + 8192 + wid * 1024); \
    gload_lds16(_sb, _db); \
    gload_lds16(_sb + (long)64 * ldb, (bf16_t*)((char*)_db + 4096)); \
  } while (0)

  const unsigned aAddr = ldsBase + (unsigned)((wm * 64 + lr) * 64) + cbyte;
  const unsigned bAddr = ldsBase + 8192u + (unsigned)((wn * 64 + lr) * 64) + cbyte;

  bf16x8_t aF[4], bF[4];
  f32x4_t acc[4][4] = {};

  const int nc = K >> 5;  // chunks of 32; multiple of 4, >= 4

#define PPH(C_, SLOT) do { \
    _Pragma("unroll") for (int _m = 0; _m < 4; ++_m) \
      aF[_m] = ds_read_b128_bf16(aAddr + (SLOT) * 16384u + _m * 1024u); \
    _Pragma("unroll") for (int _n = 0; _n < 4; ++_n) \
      bF[_n] = ds_read_b128_bf16(bAddr + (SLOT) * 16384u + _n * 1024u); \
    if ((C_) + 2 < nc) { STAGE_CH((C_) + 2, ((C_) + 2) & 3); WAIT_VM(4); } \
    else { WAIT_VM(0); } \
    __builtin_amdgcn_s_barrier(); \
    WAIT_LGKM(0); \
    SCHED_FENCE; \
    __builtin_amdgcn_s_setprio(1); \
    _Pragma("unroll") for (int _n = 0; _n < 4; ++_n) \
      _Pragma("unroll") for (int _m = 0; _m < 4; ++_m) \
        acc[_m][_n] = __builtin_amdgcn_mfma_f32_16x16x32_bf16(aF[_m], bF[_n], acc[_m][_n], 0, 0, 0); \
    __builtin_amdgcn_s_setprio(0); \
    SCHED_FENCE; \
  } while (0)

  // prologue: chunks 0,1 -> slots 0,1 (8 gloads); vmcnt(4) retires chunk 0
  STAGE_CH(0, 0); STAGE_CH(1, 1);
  WAIT_VM(4);
  __builtin_amdgcn_s_barrier();
  SCHED_FENCE;

  for (int c = 0; c < nc; c += 4) {
    PPH(c + 0, 0);
    PPH(c + 1, 1);
    PPH(c + 2, 2);
    PPH(c + 3, 3);
  }

  // epilogue: C/D layout col = lane&15, row = (lane>>4)*4 + reg
  const long r0 = (long)by * 128 + wm * 64;
  const int c0 = bx * 128 + wn * 64;
#pragma unroll
  for (int m = 0; m < 4; ++m) {
#pragma unroll
    for (int n = 0; n < 4; ++n) {
#pragma unroll
      for (int r = 0; r < 4; ++r) {
        const long row = r0 + m * 16 + lh * 4 + r;
        const int col = c0 + n * 16 + lr;
        const float v = acc[m][n][r];
        if constexpr (EPI == EPI_BIAS) {
          Cf[row * ldc + col] = v + bias[col];
        } else if constexpr (EPI == EPI_RES_BF16) {
          const float o = Res[row * ldc + col] + v;
          Cf[row * ldc + col] = o;
          Cb[row * ldc + col] = (bf16_t)o;
        } else {  // EPI_RELU_RES
          float t = v + bias[col];
          t = t > 0.f ? t : 0.f;
          const float o = Res[row * ldc + col] + t;
          Cf[row * ldc + col] = o;
          Cb[row * ldc + col] = (bf16_t)o;
        }
      }
    }
  }
#undef PPH
#undef STAGE_CH
}

// ---------------------------------------------------------------------------
// Row softmax over S f32 values; bf16 writeback to pout (compact stride S).
// ---------------------------------------------------------------------------
__global__ __launch_bounds__(256) void softmax_rows(
    const float* __restrict__ scores, bf16_t* __restrict__ pout,
    int S, long outStride)
{
  const long row = blockIdx.x;
  const float* p = scores + row * (long)S;
  bf16_t* out = pout + row * outStride;
  const int t = threadIdx.x;
  const int lane = t & 63, wave = t >> 6;

  float4 v0 = ((const float4*)p)[t * 2];
  float4 v1 = ((const float4*)p)[t * 2 + 1];
  float e[8] = {v0.x, v0.y, v0.z, v0.w, v1.x, v1.y, v1.z, v1.w};

  float m = e[0];
#pragma unroll
  for (int j = 1; j < 8; ++j) m = fmaxf(m, e[j]);
#pragma unroll
  for (int off = 32; off >= 1; off >>= 1) m = fmaxf(m, __shfl_xor(m, off));

  __shared__ float redm[4], reds[4];
  if (lane == 0) redm[wave] = m;
  __syncthreads();
  m = fmaxf(fmaxf(redm[0], redm[1]), fmaxf(redm[2], redm[3]));

  float s = 0.f;
#pragma unroll
  for (int j = 0; j < 8; ++j) { e[j] = __expf(e[j] - m); s += e[j]; }
#pragma unroll
  for (int off = 32; off >= 1; off >>= 1) s += __shfl_xor(s, off);
  if (lane == 0) reds[wave] = s;
  __syncthreads();
  s = reds[0] + reds[1] + reds[2] + reds[3];
  const float inv = 1.f / s;

  bf16x8_t ob;
#pragma unroll
  for (int j = 0; j < 8; ++j) ob[j] = (bf16_t)(e[j] * inv);
  ((bf16x8_t*)out)[t] = ob;
}

// ---------------------------------------------------------------------------
__global__ void cast_copy(const float* __restrict__ in, float* __restrict__ outf,
                          bf16_t* __restrict__ outb, long n4)
{
  long i = (long)blockIdx.x * blockDim.x + threadIdx.x;
  const long stride = (long)gridDim.x * blockDim.x;
  for (; i < n4; i += stride) {
    float4 v = ((const float4*)in)[i];
    ((float4*)outf)[i] = v;
    bf16x4_t bv;
    bv[0] = (bf16_t)v.x; bv[1] = (bf16_t)v.y; bv[2] = (bf16_t)v.z; bv[3] = (bf16_t)v.w;
    ((bf16x4_t*)outb)[i] = bv;
  }
}

// ---------------------------------------------------------------------------
__global__ void transpose_cast(const float* __restrict__ in, long inBatch, int R, int C,
                               bf16_t* __restrict__ out, long outBatch)
{
  __shared__ float tile[32][33];
  const float* src = in + (long)blockIdx.z * inBatch;
  bf16_t* dst = out + (long)blockIdx.z * outBatch;
  const int c0 = blockIdx.x * 32, r0 = blockIdx.y * 32;
  const int tx = threadIdx.x, ty = threadIdx.y;
#pragma unroll
  for (int i = 0; i < 32; i += 8) tile[ty + i][tx] = src[(long)(r0 + ty + i) * C + (c0 + tx)];
  __syncthreads();
#pragma unroll
  for (int i = 0; i < 32; i += 8)
    dst[(long)(c0 + ty + i) * R + (r0 + tx)] = (bf16_t)tile[tx][ty + i];
}

// ---------------------------------------------------------------------------
extern "C" void kernel_launch(void* const* d_in, const int* in_sizes, int n_in,
                              void* d_out, int out_size, void* d_ws, size_t ws_size,
                              hipStream_t stream)
{
  constexpr int L = 4, NB = 4, S = 2048, D = 1024;
  const float* x  = (const float*)d_in[0];
  const float* W  = (const float*)d_in[1];
  const float* bv = (const float*)d_in[2];
  const float* Wo = (const float*)d_in[3];
  const float* bo = (const float*)d_in[4];

  char* ws = (char*)d_ws;
  size_t off = 0;
  float* scores = (float*)(ws + off); off += (size_t)NB * S * S * 4;
  float* xf = (float*)(ws + off); off += (size_t)NB * S * D * 4;
  float* yf = (float*)(ws + off); off += (size_t)NB * S * D * 4;
  bf16_t* xb  = (bf16_t*)(ws + off); off += (size_t)NB * S * D * 2;
  bf16_t* xbT = (bf16_t*)(ws + off); off += (size_t)NB * S * D * 2;
  bf16_t* yb  = (bf16_t*)(ws + off); off += (size_t)NB * S * D * 2;
  bf16_t* WbT  = (bf16_t*)(ws + off); off += (size_t)L * D * D * 2;
  bf16_t* WobT = (bf16_t*)(ws + off); off += (size_t)D * D * 2;

  // Compact bf16 P buffer (stride S) if workspace permits; else in-place.
  const size_t pbBytes = (size_t)NB * S * S * 2;
  bf16_t* Pb = nullptr;
  if (off + pbBytes <= ws_size) { Pb = (bf16_t*)(ws + off); off += pbBytes; }
  const bool compact = (Pb != nullptr);
  bf16_t* pOut = compact ? Pb : (bf16_t*)scores;
  const long pStride = compact ? (long)S : (long)2 * S;
  const long pBatch  = compact ? (long)S * S : (long)2 * S * S;

  hipFuncSetAttribute((const void*)gemm256_bt_scale,
                      hipFuncAttributeMaxDynamicSharedMemorySize, 131072);
  hipFuncSetAttribute((const void*)gemm128_bt<EPI_RES_BF16>,
                      hipFuncAttributeMaxDynamicSharedMemorySize, 65536);
  hipFuncSetAttribute((const void*)gemm128_bt<EPI_RELU_RES>,
                      hipFuncAttributeMaxDynamicSharedMemorySize, 65536);
  hipFuncSetAttribute((const void*)gemm128_bt<EPI_BIAS>,
                      hipFuncAttributeMaxDynamicSharedMemorySize, 65536);

  const long n4 = (long)NB * S * D / 4;
  cast_copy<<<2048, 256, 0, stream>>>(x, xf, xb, n4);
  transpose_cast<<<dim3(D / 32, S / 32, NB), dim3(32, 8), 0, stream>>>(
      x, (long)S * D, S, D, xbT, (long)D * S);
  transpose_cast<<<dim3(D / 32, D / 32, L), dim3(32, 8), 0, stream>>>(
      W, (long)D * D, D, D, WbT, (long)D * D);
  transpose_cast<<<dim3(D / 32, D / 32, 1), dim3(32, 8), 0, stream>>>(
      Wo, 0, D, D, WobT, 0);

  const float inv_sqrt_d = 0.03125f;  // 1/sqrt(1024)

  for (int i = 0; i < L; ++i) {
    // scores = xb @ xb^T * inv_sqrt_d
    gemm256_bt_scale<<<dim3(S / 256, S / 256, NB), 512, 131072, stream>>>(
        xb, (long)S * D, D, xb, (long)S * D, D,
        scores, (long)S * S, S, inv_sqrt_d, D);
    // softmax rows -> compact bf16 P
    softmax_rows<<<NB * S, 256, 0, stream>>>(scores, pOut, S, pStride);
    // y = xf + P @ x   (Bt = xbT) — 128x128 tile, 2 wg/CU
    gemm128_bt<EPI_RES_BF16><<<dim3(D / 128, S / 128, NB), 256, 65536, stream>>>(
        pOut, pBatch, (int)pStride, xbT, (long)D * S, S,
        yf, (long)S * D, D, yb, (long)S * D, xf, (long)S * D, nullptr, S);
    // z = yf + relu(yb @ W[i] + b[i])  -> xf, xb
    gemm128_bt<EPI_RELU_RES><<<dim3(D / 128, (NB * S) / 128, 1), 256, 65536, stream>>>(
        yb, 0, D, WbT + (size_t)i * D * D, 0, D,
        xf, 0, D, xb, 0, yf, 0, bv + (size_t)i * D, D);
    if (i < L - 1)
      transpose_cast<<<dim3(D / 32, S / 32, NB), dim3(32, 8), 0, stream>>>(
          xf, (long)S * D, S, D, xbT, (long)D * S);
  }

  // out = xb @ Wo + bo
  gemm128_bt<EPI_BIAS><<<dim3(D / 128, (NB * S) / 128, 1), 256, 65536, stream>>>(
      xb, 0, D, WobT, 0, D,
      (float*)d_out, 0, D, nullptr, 0, nullptr, 0, bo, D);
}